// Round 11
// baseline (162.551 us; speedup 1.0000x reference)
//
#include <hip/hip_runtime.h>
#include <hip/hip_bf16.h>

#define LOG2E 1.44269504088896340736f

typedef __attribute__((ext_vector_type(8))) short short8;
typedef __attribute__((ext_vector_type(4))) float floatx4;

static __device__ __forceinline__ short f2bf(float f) {
    union { float f; unsigned u; } v; v.f = f;
    unsigned r = (v.u + 0x7FFF + ((v.u >> 16) & 1)) >> 16;  // RNE
    return (short)r;
}

static __device__ __forceinline__ floatx4 mfma16(short8 a, short8 b, floatx4 c) {
    return __builtin_amdgcn_mfma_f32_16x16x32_bf16(a, b, c, 0, 0, 0);
}

static __device__ __forceinline__ unsigned cvt_pk_bf16(float lo, float hi) {
    unsigned u;
    asm("v_cvt_pk_bf16_f32 %0, %1, %2" : "=v"(u) : "v"(lo), "v"(hi));
    return u;
}

// ---------------- Weight pre-convert: wb tiled [(ot*16+cg)][64 o][32 c] ----------------
__global__ __launch_bounds__(256) void wcvt_kernel(
    const float* __restrict__ wq, const float* __restrict__ wk,
    const float* __restrict__ wv, short* __restrict__ wb)
{
    const int idx = (blockIdx.x * 256 + threadIdx.x) * 4;   // 294912 total
    const int row = idx >> 9;          // 0..575
    const int col = idx & 511;
    const float* src;
    float sc = 1.0f;
    if (row < 32)      { src = wq + (size_t)row * 512; sc = LOG2E; }
    else if (row < 64) { src = wk + (size_t)(row - 32) * 512; }
    else               { src = wv + (size_t)(row - 64) * 512; }
    floatx4 v = *(const floatx4*)(src + col);
    union { short s[4]; long long ll; } o;
#pragma unroll
    for (int u = 0; u < 4; u++) o.s[u] = f2bf(v[u] * sc);
    const int didx = (((row >> 6) * 16 + (col >> 5)) * 64 + (row & 63)) * 32 + (col & 31);
    *(long long*)(wb + didx) = o.ll;
}

// ---------------- Projection: x read ONCE; W reads contiguous ----------------
__global__ __launch_bounds__(256) void proj_kernel(
    const float* __restrict__ x, const short* __restrict__ wb,
    const float* __restrict__ bq, const float* __restrict__ bk,
    const float* __restrict__ bv,
    short* __restrict__ qT, short* __restrict__ kT, short* __restrict__ vm)
{
    __shared__ short xT[32 * 520];   // [n][c] bf16, pitch 520
    const int tid = threadIdx.x;
    const int w = tid >> 6;
    const int lane = tid & 63;
    const int l15 = lane & 15, l4 = lane >> 4;
    const int n0 = blockIdx.x * 32;
    const int b  = blockIdx.y;

    const float* xb = x + (size_t)b * 512 * 4096;

    const int cp = tid >> 3;          // 0..31
    const int nq = (tid & 7) * 4;     // 0,4,..,28
#pragma unroll
    for (int p = 0; p < 8; p++) {
        const int c = (p * 32 + cp) * 2;
        const float* r0 = xb + (size_t)c * 4096 + n0 + nq;
        const float* r1 = r0 + 4096;
        floatx4 xa = *(const floatx4*)r0;
        floatx4 xc = *(const floatx4*)r1;
#pragma unroll
        for (int u = 0; u < 4; u++)
            *(unsigned*)&xT[(nq + u) * 520 + c] = cvt_pk_bf16(xa[u], xc[u]);
    }
    __syncthreads();

#pragma unroll 1
    for (int ot = 0; ot < 9; ot++) {
        floatx4 acc[2];
#pragma unroll
        for (int i = 0; i < 2; i++) acc[i] = (floatx4)(0.0f);

#pragma unroll 4
        for (int c0 = 0; c0 < 512; c0 += 32) {
            short8 af = *(const short8*)(wb + ((size_t)(ot * 16 + (c0 >> 5)) * 64
                                               + w * 16 + l15) * 32 + 8 * l4);
#pragma unroll
            for (int nt = 0; nt < 2; nt++) {
                short8 bf = *(const short8*)&xT[(nt * 16 + l15) * 520 + c0 + 8 * l4];
                acc[nt] = mfma16(af, bf, acc[nt]);
            }
        }

#pragma unroll
        for (int r = 0; r < 4; r++) {
            const int o_d = ot * 64 + w * 16 + 4 * l4 + r;
#pragma unroll
            for (int nt = 0; nt < 2; nt++) {
                const int n = n0 + nt * 16 + l15;
                const float val = acc[nt][r];
                if (o_d < 32) {
                    qT[((size_t)(b * 4096 + n)) * 32 + o_d] = f2bf(val + bq[o_d] * LOG2E);
                } else if (o_d < 64) {
                    const int s = n & 31;
                    const int p2 = 16 * ((s >> 2) & 1) + 4 * (s >> 3) + (s & 3);
                    const int nst = (n & ~31) | p2;
                    kT[((size_t)(b * 4096 + nst)) * 32 + (o_d - 32)] = f2bf(val + bk[o_d - 32]);
                } else {
                    const int c = o_d - 64;
                    vm[((size_t)((b * 128 + blockIdx.x) * 512 + c)) * 32
                       + (nt * 16 + l15)] = f2bf(val + bv[c]);
                }
            }
        }
    }
}

// ---------------- Flash attention + residual ----------------
// 512 blocks x 8 waves, 2 blocks/CU (4 waves/SIMD). Block = (b, c-half, q-tile
// of 64); wave covers 32 c. All 8 waves produce P (j-macro=256, wave w owns
// j slice w*32..+32) -> P duplicated across the ch pair (cheap trans-pipe work)
// but V L2 traffic stays 1 GB. Tiled V loads (contiguous 1KB). dbuf P 64 KB.
__global__ __launch_bounds__(512, 4) void attn_kernel(
    const short* __restrict__ qT, const short* __restrict__ kT,
    const short* __restrict__ vm, const float* __restrict__ x,
    const float* __restrict__ gamma, float* __restrict__ out)
{
    __shared__ short P_lds[2][32 * 512];   // [buf][frag = w*4+it][lane*8]
    __shared__ float red_lds[8][64];
    const int tid = threadIdx.x;
    const int lane = tid & 63;
    const int w = tid >> 6;
    const int l15 = lane & 15, l4 = lane >> 4;

    // XCD decode: xcd = b*2+ch; its 64 blocks (2/CU) share a 2 MB V slice in L2
    const int bid = blockIdx.x;
    const int xcd = bid & 7;
    const int qt  = bid >> 3;            // 0..63
    const int b   = xcd >> 1;
    const int ch  = xcd & 1;
    const int i0  = qt * 64;
    const int cb  = ch * 256 + w * 32;

    short8 qf[4];
#pragma unroll
    for (int it = 0; it < 4; it++)
        qf[it] = *(const short8*)(qT + ((size_t)(b * 4096 + i0 + it * 16 + l15)) * 32 + 8 * l4);

    floatx4 acc[2][4];   // [ct][it]
#pragma unroll
    for (int ct = 0; ct < 2; ct++)
#pragma unroll
        for (int it = 0; it < 4; it++) acc[ct][it] = (floatx4)(0.0f);

    float l_[4] = {0.0f, 0.0f, 0.0f, 0.0f};

    const short* kb = kT + (size_t)b * 4096 * 32;
    const short* vb = vm + (size_t)b * 512 * 4096;   // tiled [jt][512][32]

#define PROD(T, KF0, KF1)                                                            \
    {                                                                                \
        const int buf = (T) & 1;                                                     \
        _Pragma("unroll")                                                            \
        for (int it = 0; it < 4; it++) {                                             \
            floatx4 s0 = mfma16((KF0), qf[it], (floatx4)(0.0f));                     \
            floatx4 s1 = mfma16((KF1), qf[it], (floatx4)(0.0f));                     \
            float p[8];                                                              \
            _Pragma("unroll")                                                        \
            for (int r = 0; r < 4; r++) {                                            \
                p[r]     = __builtin_amdgcn_exp2f(s0[r]);                            \
                p[4 + r] = __builtin_amdgcn_exp2f(s1[r]);                            \
            }                                                                        \
            union { short8 s; unsigned u[4]; } pk;                                   \
            _Pragma("unroll")                                                        \
            for (int j2 = 0; j2 < 4; j2++) pk.u[j2] = cvt_pk_bf16(p[2*j2], p[2*j2+1]); \
            *(short8*)&P_lds[buf][(w * 4 + it) * 512 + lane * 8] = pk.s;             \
            l_[it] += ((p[0] + p[1]) + (p[2] + p[3])) + ((p[4] + p[5]) + (p[6] + p[7])); \
        }                                                                            \
    }

#define VLOAD(T, JG, CT)                                                             \
    (*(const short8*)(vb + ((size_t)(((T) * 8 + (JG)) * 512 + cb + (CT) * 16 + l15)) * 32 + 8 * l4))
#define PREAD(BUF, JG, IT)                                                           \
    (*(const short8*)&P_lds[BUF][((JG) * 4 + (IT)) * 512 + lane * 8])

#define CONSUME(T)                                                                   \
    {                                                                                \
        const int buf = (T) & 1;                                                     \
        short8 vfp[2][2];                                                            \
        short8 pcp[2][4];                                                            \
        _Pragma("unroll")                                                            \
        for (int ct = 0; ct < 2; ct++) vfp[0][ct] = VLOAD(T, 0, ct);                 \
        _Pragma("unroll")                                                            \
        for (int it = 0; it < 4; it++) pcp[0][it] = PREAD(buf, 0, it);               \
        _Pragma("unroll")                                                            \
        for (int jg = 0; jg < 8; jg++) {                                             \
            if (jg < 7) {                                                            \
                _Pragma("unroll")                                                    \
                for (int ct = 0; ct < 2; ct++)                                       \
                    vfp[(jg + 1) & 1][ct] = VLOAD(T, jg + 1, ct);                    \
                _Pragma("unroll")                                                    \
                for (int it = 0; it < 4; it++)                                       \
                    pcp[(jg + 1) & 1][it] = PREAD(buf, jg + 1, it);                  \
            }                                                                        \
            __builtin_amdgcn_s_setprio(1);                                           \
            _Pragma("unroll")                                                        \
            for (int ct = 0; ct < 2; ct++)                                           \
                _Pragma("unroll")                                                    \
                for (int it = 0; it < 4; it++)                                       \
                    acc[ct][it] = mfma16(vfp[jg & 1][ct], pcp[jg & 1][it], acc[ct][it]); \
            __builtin_amdgcn_s_setprio(0);                                           \
        }                                                                            \
    }

    // prologue: produce macro-tile 0
    {
        short8 kf0 = *(const short8*)(kb + (size_t)(w * 32 + l15) * 32 + 8 * l4);
        short8 kf1 = *(const short8*)(kb + (size_t)(w * 32 + 16 + l15) * 32 + 8 * l4);
        PROD(0, kf0, kf1);
    }

#pragma unroll 1
    for (int t = 0; t < 16; t++) {
        __syncthreads();
        short8 nk0, nk1;
        if (t < 15) {   // hoist next K loads; latency hides under CONSUME
            const int jj = (t + 1) * 256 + w * 32;
            nk0 = *(const short8*)(kb + (size_t)(jj + l15) * 32 + 8 * l4);
            nk1 = *(const short8*)(kb + (size_t)(jj + 16 + l15) * 32 + 8 * l4);
        }
        CONSUME(t);
        if (t < 15) PROD(t + 1, nk0, nk1);
    }
#undef PROD
#undef CONSUME
#undef VLOAD
#undef PREAD

    // l: reduce within wave, then across 8 waves via LDS
#pragma unroll
    for (int it = 0; it < 4; it++) {
        l_[it] += __shfl_xor(l_[it], 16, 64);
        l_[it] += __shfl_xor(l_[it], 32, 64);
    }
    if (lane < 16)
#pragma unroll
        for (int it = 0; it < 4; it++) red_lds[w][it * 16 + lane] = l_[it];
    __syncthreads();

    const float g = gamma[0];
    float inv[4];
#pragma unroll
    for (int it = 0; it < 4; it++) {
        float s = 0.0f;
#pragma unroll
        for (int ww = 0; ww < 8; ww++) s += red_lds[ww][it * 16 + l15];
        inv[it] = g / s;
    }

#pragma unroll
    for (int ct = 0; ct < 2; ct++)
#pragma unroll
        for (int it = 0; it < 4; it++)
#pragma unroll
            for (int r = 0; r < 4; r++) {
                const int c = cb + ct * 16 + 4 * l4 + r;
                const int i = i0 + it * 16 + l15;
                const size_t o = ((size_t)(b * 512 + c)) * 4096 + i;
                out[o] = acc[ct][it][r] * inv[it] + x[o];
            }
}

extern "C" void kernel_launch(void* const* d_in, const int* in_sizes, int n_in,
                              void* d_out, int out_size, void* d_ws, size_t ws_size,
                              hipStream_t stream) {
    const float* x     = (const float*)d_in[0];
    const float* wq    = (const float*)d_in[1];
    const float* bq    = (const float*)d_in[2];
    const float* wk    = (const float*)d_in[3];
    const float* bk    = (const float*)d_in[4];
    const float* wv    = (const float*)d_in[5];
    const float* bv    = (const float*)d_in[6];
    const float* gamma = (const float*)d_in[7];
    float* out = (float*)d_out;

    short* qT = (short*)d_ws;                  // 1 MB
    short* kT = qT + (size_t)4 * 4096 * 32;    // 1 MB
    short* vm = kT + (size_t)4 * 4096 * 32;    // 16 MB (tiled [b][jt][512][32])
    short* wb = vm + (size_t)4 * 512 * 4096;   // 0.56 MB (tiled)

    wcvt_kernel<<<288, 256, 0, stream>>>(wq, wk, wv, wb);
    proj_kernel<<<dim3(128, 4), 256, 0, stream>>>(x, wb, bq, bk, bv, qT, kT, vm);
    attn_kernel<<<512, 512, 0, stream>>>(qT, kT, vm, x, gamma, out);
}

// Round 12
// 151.864 us; speedup vs baseline: 1.0704x; 1.0704x over previous
//
#include <hip/hip_runtime.h>
#include <hip/hip_bf16.h>

#define LOG2E 1.44269504088896340736f

typedef __attribute__((ext_vector_type(8))) short short8;
typedef __attribute__((ext_vector_type(4))) float floatx4;

static __device__ __forceinline__ short f2bf(float f) {
    union { float f; unsigned u; } v; v.f = f;
    unsigned r = (v.u + 0x7FFF + ((v.u >> 16) & 1)) >> 16;  // RNE
    return (short)r;
}

static __device__ __forceinline__ floatx4 mfma16(short8 a, short8 b, floatx4 c) {
    return __builtin_amdgcn_mfma_f32_16x16x32_bf16(a, b, c, 0, 0, 0);
}

static __device__ __forceinline__ unsigned cvt_pk_bf16(float lo, float hi) {
    unsigned u;
    asm("v_cvt_pk_bf16_f32 %0, %1, %2" : "=v"(u) : "v"(lo), "v"(hi));
    return u;
}

// ---------------- Weight pre-convert: wb tiled [(ot*16+cg)][64 o][32 c] ----------------
__global__ __launch_bounds__(256) void wcvt_kernel(
    const float* __restrict__ wq, const float* __restrict__ wk,
    const float* __restrict__ wv, short* __restrict__ wb)
{
    const int idx = (blockIdx.x * 256 + threadIdx.x) * 4;   // 294912 total
    const int row = idx >> 9;          // 0..575
    const int col = idx & 511;
    const float* src;
    float sc = 1.0f;
    if (row < 32)      { src = wq + (size_t)row * 512; sc = LOG2E; }
    else if (row < 64) { src = wk + (size_t)(row - 32) * 512; }
    else               { src = wv + (size_t)(row - 64) * 512; }
    floatx4 v = *(const floatx4*)(src + col);
    union { short s[4]; long long ll; } o;
#pragma unroll
    for (int u = 0; u < 4; u++) o.s[u] = f2bf(v[u] * sc);
    const int didx = (((row >> 6) * 16 + (col >> 5)) * 64 + (row & 63)) * 32 + (col & 31);
    *(long long*)(wb + didx) = o.ll;
}

// ---------------- Projection: x read ONCE; W reads contiguous ----------------
__global__ __launch_bounds__(256) void proj_kernel(
    const float* __restrict__ x, const short* __restrict__ wb,
    const float* __restrict__ bq, const float* __restrict__ bk,
    const float* __restrict__ bv,
    short* __restrict__ qT, short* __restrict__ kT, short* __restrict__ vm)
{
    __shared__ short xT[32 * 520];   // [n][c] bf16, pitch 520
    const int tid = threadIdx.x;
    const int w = tid >> 6;
    const int lane = tid & 63;
    const int l15 = lane & 15, l4 = lane >> 4;
    const int n0 = blockIdx.x * 32;
    const int b  = blockIdx.y;

    const float* xb = x + (size_t)b * 512 * 4096;

    const int cp = tid >> 3;          // 0..31
    const int nq = (tid & 7) * 4;     // 0,4,..,28
#pragma unroll
    for (int p = 0; p < 8; p++) {
        const int c = (p * 32 + cp) * 2;
        const float* r0 = xb + (size_t)c * 4096 + n0 + nq;
        const float* r1 = r0 + 4096;
        floatx4 xa = *(const floatx4*)r0;
        floatx4 xc = *(const floatx4*)r1;
#pragma unroll
        for (int u = 0; u < 4; u++)
            *(unsigned*)&xT[(nq + u) * 520 + c] = cvt_pk_bf16(xa[u], xc[u]);
    }
    __syncthreads();

#pragma unroll 1
    for (int ot = 0; ot < 9; ot++) {
        floatx4 acc[2];
#pragma unroll
        for (int i = 0; i < 2; i++) acc[i] = (floatx4)(0.0f);

#pragma unroll 4
        for (int c0 = 0; c0 < 512; c0 += 32) {
            short8 af = *(const short8*)(wb + ((size_t)(ot * 16 + (c0 >> 5)) * 64
                                               + w * 16 + l15) * 32 + 8 * l4);
#pragma unroll
            for (int nt = 0; nt < 2; nt++) {
                short8 bf = *(const short8*)&xT[(nt * 16 + l15) * 520 + c0 + 8 * l4];
                acc[nt] = mfma16(af, bf, acc[nt]);
            }
        }

#pragma unroll
        for (int r = 0; r < 4; r++) {
            const int o_d = ot * 64 + w * 16 + 4 * l4 + r;
#pragma unroll
            for (int nt = 0; nt < 2; nt++) {
                const int n = n0 + nt * 16 + l15;
                const float val = acc[nt][r];
                if (o_d < 32) {
                    qT[((size_t)(b * 4096 + n)) * 32 + o_d] = f2bf(val + bq[o_d] * LOG2E);
                } else if (o_d < 64) {
                    const int s = n & 31;
                    const int p2 = 16 * ((s >> 2) & 1) + 4 * (s >> 3) + (s & 3);
                    const int nst = (n & ~31) | p2;
                    kT[((size_t)(b * 4096 + nst)) * 32 + (o_d - 32)] = f2bf(val + bk[o_d - 32]);
                } else {
                    const int c = o_d - 64;
                    vm[((size_t)((b * 128 + blockIdx.x) * 512 + c)) * 32
                       + (nt * 16 + l15)] = f2bf(val + bv[c]);
                }
            }
        }
    }
}

// ---------------- Flash attention + residual ----------------
// 512 blocks x 8 waves, 2 blocks/CU (LDS 66 KB). Block = (b, c-half, q-tile
// of 64); wave covers 32 c. P duplicated across the ch pair (cheap); V L2
// traffic stays 1 GB. Tiled V loads (contiguous 1KB). dbuf P 64 KB.
// launch_bounds(512,1): min-waves hints >1 force VGPR caps + spills (R3/R10).
__global__ __launch_bounds__(512, 1) void attn_kernel(
    const short* __restrict__ qT, const short* __restrict__ kT,
    const short* __restrict__ vm, const float* __restrict__ x,
    const float* __restrict__ gamma, float* __restrict__ out)
{
    __shared__ short P_lds[2][32 * 512];   // [buf][frag = w*4+it][lane*8]
    __shared__ float red_lds[8][64];
    const int tid = threadIdx.x;
    const int lane = tid & 63;
    const int w = tid >> 6;
    const int l15 = lane & 15, l4 = lane >> 4;

    // XCD decode: xcd = b*2+ch; its 64 blocks (2/CU) share a 2 MB V slice in L2
    const int bid = blockIdx.x;
    const int xcd = bid & 7;
    const int qt  = bid >> 3;            // 0..63
    const int b   = xcd >> 1;
    const int ch  = xcd & 1;
    const int i0  = qt * 64;
    const int cb  = ch * 256 + w * 32;

    short8 qf[4];
#pragma unroll
    for (int it = 0; it < 4; it++)
        qf[it] = *(const short8*)(qT + ((size_t)(b * 4096 + i0 + it * 16 + l15)) * 32 + 8 * l4);

    floatx4 acc[2][4];   // [ct][it]
#pragma unroll
    for (int ct = 0; ct < 2; ct++)
#pragma unroll
        for (int it = 0; it < 4; it++) acc[ct][it] = (floatx4)(0.0f);

    float l_[4] = {0.0f, 0.0f, 0.0f, 0.0f};

    const short* kb = kT + (size_t)b * 4096 * 32;
    const short* vb = vm + (size_t)b * 512 * 4096;   // tiled [jt][512][32]

#define PROD(T, KF0, KF1)                                                            \
    {                                                                                \
        const int buf = (T) & 1;                                                     \
        _Pragma("unroll")                                                            \
        for (int it = 0; it < 4; it++) {                                             \
            floatx4 s0 = mfma16((KF0), qf[it], (floatx4)(0.0f));                     \
            floatx4 s1 = mfma16((KF1), qf[it], (floatx4)(0.0f));                     \
            float p[8];                                                              \
            _Pragma("unroll")                                                        \
            for (int r = 0; r < 4; r++) {                                            \
                p[r]     = __builtin_amdgcn_exp2f(s0[r]);                            \
                p[4 + r] = __builtin_amdgcn_exp2f(s1[r]);                            \
            }                                                                        \
            union { short8 s; unsigned u[4]; } pk;                                   \
            _Pragma("unroll")                                                        \
            for (int j2 = 0; j2 < 4; j2++) pk.u[j2] = cvt_pk_bf16(p[2*j2], p[2*j2+1]); \
            *(short8*)&P_lds[buf][(w * 4 + it) * 512 + lane * 8] = pk.s;             \
            l_[it] += ((p[0] + p[1]) + (p[2] + p[3])) + ((p[4] + p[5]) + (p[6] + p[7])); \
        }                                                                            \
    }

#define VLOAD(T, JG, CT)                                                             \
    (*(const short8*)(vb + ((size_t)(((T) * 8 + (JG)) * 512 + cb + (CT) * 16 + l15)) * 32 + 8 * l4))
#define PREAD(BUF, JG, IT)                                                           \
    (*(const short8*)&P_lds[BUF][((JG) * 4 + (IT)) * 512 + lane * 8])

#define CONSUME(T)                                                                   \
    {                                                                                \
        const int buf = (T) & 1;                                                     \
        short8 vfp[2][2];                                                            \
        short8 pcp[2][4];                                                            \
        _Pragma("unroll")                                                            \
        for (int ct = 0; ct < 2; ct++) vfp[0][ct] = VLOAD(T, 0, ct);                 \
        _Pragma("unroll")                                                            \
        for (int it = 0; it < 4; it++) pcp[0][it] = PREAD(buf, 0, it);               \
        _Pragma("unroll")                                                            \
        for (int jg = 0; jg < 8; jg++) {                                             \
            if (jg < 7) {                                                            \
                _Pragma("unroll")                                                    \
                for (int ct = 0; ct < 2; ct++)                                       \
                    vfp[(jg + 1) & 1][ct] = VLOAD(T, jg + 1, ct);                    \
                _Pragma("unroll")                                                    \
                for (int it = 0; it < 4; it++)                                       \
                    pcp[(jg + 1) & 1][it] = PREAD(buf, jg + 1, it);                  \
            }                                                                        \
            __builtin_amdgcn_s_setprio(1);                                           \
            _Pragma("unroll")                                                        \
            for (int ct = 0; ct < 2; ct++)                                           \
                _Pragma("unroll")                                                    \
                for (int it = 0; it < 4; it++)                                       \
                    acc[ct][it] = mfma16(vfp[jg & 1][ct], pcp[jg & 1][it], acc[ct][it]); \
            __builtin_amdgcn_s_setprio(0);                                           \
        }                                                                            \
    }

    // prologue: produce macro-tile 0
    {
        short8 kf0 = *(const short8*)(kb + (size_t)(w * 32 + l15) * 32 + 8 * l4);
        short8 kf1 = *(const short8*)(kb + (size_t)(w * 32 + 16 + l15) * 32 + 8 * l4);
        PROD(0, kf0, kf1);
    }

#pragma unroll 1
    for (int t = 0; t < 16; t++) {
        __syncthreads();
        short8 nk0, nk1;
        if (t < 15) {   // hoist next K loads; latency hides under CONSUME
            const int jj = (t + 1) * 256 + w * 32;
            nk0 = *(const short8*)(kb + (size_t)(jj + l15) * 32 + 8 * l4);
            nk1 = *(const short8*)(kb + (size_t)(jj + 16 + l15) * 32 + 8 * l4);
        }
        CONSUME(t);
        if (t < 15) PROD(t + 1, nk0, nk1);
    }
#undef PROD
#undef CONSUME
#undef VLOAD
#undef PREAD

    // l: reduce within wave, then across 8 waves via LDS
#pragma unroll
    for (int it = 0; it < 4; it++) {
        l_[it] += __shfl_xor(l_[it], 16, 64);
        l_[it] += __shfl_xor(l_[it], 32, 64);
    }
    if (lane < 16)
#pragma unroll
        for (int it = 0; it < 4; it++) red_lds[w][it * 16 + lane] = l_[it];
    __syncthreads();

    const float g = gamma[0];
    float inv[4];
#pragma unroll
    for (int it = 0; it < 4; it++) {
        float s = 0.0f;
#pragma unroll
        for (int ww = 0; ww < 8; ww++) s += red_lds[ww][it * 16 + l15];
        inv[it] = g / s;
    }

#pragma unroll
    for (int ct = 0; ct < 2; ct++)
#pragma unroll
        for (int it = 0; it < 4; it++)
#pragma unroll
            for (int r = 0; r < 4; r++) {
                const int c = cb + ct * 16 + 4 * l4 + r;
                const int i = i0 + it * 16 + l15;
                const size_t o = ((size_t)(b * 512 + c)) * 4096 + i;
                out[o] = acc[ct][it][r] * inv[it] + x[o];
            }
}

extern "C" void kernel_launch(void* const* d_in, const int* in_sizes, int n_in,
                              void* d_out, int out_size, void* d_ws, size_t ws_size,
                              hipStream_t stream) {
    const float* x     = (const float*)d_in[0];
    const float* wq    = (const float*)d_in[1];
    const float* bq    = (const float*)d_in[2];
    const float* wk    = (const float*)d_in[3];
    const float* bk    = (const float*)d_in[4];
    const float* wv    = (const float*)d_in[5];
    const float* bv    = (const float*)d_in[6];
    const float* gamma = (const float*)d_in[7];
    float* out = (float*)d_out;

    short* qT = (short*)d_ws;                  // 1 MB
    short* kT = qT + (size_t)4 * 4096 * 32;    // 1 MB
    short* vm = kT + (size_t)4 * 4096 * 32;    // 16 MB (tiled [b][jt][512][32])
    short* wb = vm + (size_t)4 * 512 * 4096;   // 0.56 MB (tiled)

    wcvt_kernel<<<288, 256, 0, stream>>>(wq, wk, wv, wb);
    proj_kernel<<<dim3(128, 4), 256, 0, stream>>>(x, wb, bq, bk, bv, qT, kT, vm);
    attn_kernel<<<512, 512, 0, stream>>>(qT, kT, vm, x, gamma, out);
}

// Round 13
// 148.517 us; speedup vs baseline: 1.0945x; 1.0225x over previous
//
#include <hip/hip_runtime.h>
#include <hip/hip_bf16.h>

#define LOG2E 1.44269504088896340736f

typedef __attribute__((ext_vector_type(8))) short short8;
typedef __attribute__((ext_vector_type(4))) float floatx4;

static __device__ __forceinline__ short f2bf(float f) {
    union { float f; unsigned u; } v; v.f = f;
    unsigned r = (v.u + 0x7FFF + ((v.u >> 16) & 1)) >> 16;  // RNE
    return (short)r;
}

static __device__ __forceinline__ floatx4 mfma16(short8 a, short8 b, floatx4 c) {
    return __builtin_amdgcn_mfma_f32_16x16x32_bf16(a, b, c, 0, 0, 0);
}

static __device__ __forceinline__ unsigned cvt_pk_bf16(float lo, float hi) {
    unsigned u;
    asm("v_cvt_pk_bf16_f32 %0, %1, %2" : "=v"(u) : "v"(lo), "v"(hi));
    return u;
}

// ---------------- Weight pre-convert: wb tiled [(ot*16+cg)][64 o][32 c] ----------------
__global__ __launch_bounds__(256) void wcvt_kernel(
    const float* __restrict__ wq, const float* __restrict__ wk,
    const float* __restrict__ wv, short* __restrict__ wb)
{
    const int idx = (blockIdx.x * 256 + threadIdx.x) * 4;   // 294912 total
    const int row = idx >> 9;          // 0..575
    const int col = idx & 511;
    const float* src;
    float sc = 1.0f;
    if (row < 32)      { src = wq + (size_t)row * 512; sc = LOG2E; }
    else if (row < 64) { src = wk + (size_t)(row - 32) * 512; }
    else               { src = wv + (size_t)(row - 64) * 512; }
    floatx4 v = *(const floatx4*)(src + col);
    union { short s[4]; long long ll; } o;
#pragma unroll
    for (int u = 0; u < 4; u++) o.s[u] = f2bf(v[u] * sc);
    const int didx = (((row >> 6) * 16 + (col >> 5)) * 64 + (row & 63)) * 32 + (col & 31);
    *(long long*)(wb + didx) = o.ll;
}

// ---------------- Projection v2: n-tile 16, 4 blocks/CU ----------------
// grid (256 n-tiles of 16, B), block 256 (4 waves), LDS 16.6 KB -> 4 blocks/CU.
// x read once (32 MB). W reads contiguous (tiled wb). Outputs identical layouts:
// qT [b][n][32], kT row-permuted, vm tiled [b][n>>5][512 c][n&31].
__global__ __launch_bounds__(256) void proj_kernel(
    const float* __restrict__ x, const short* __restrict__ wb,
    const float* __restrict__ bq, const float* __restrict__ bk,
    const float* __restrict__ bv,
    short* __restrict__ qT, short* __restrict__ kT, short* __restrict__ vm)
{
    __shared__ short xT[16 * 520];   // [n][c] bf16, pitch 520
    const int tid = threadIdx.x;
    const int w = tid >> 6;
    const int lane = tid & 63;
    const int l15 = lane & 15, l4 = lane >> 4;
    const int n0 = blockIdx.x * 16;
    const int b  = blockIdx.y;

    const float* xb = x + (size_t)b * 512 * 4096;

    // staging: pass p -> thread covers (c = p*64 + tid>>2, n-quad = (tid&3)*4).
    // Each float4 = one fully-consumed 64B line; 4 lanes cover a full row chunk.
    const int sc_ = tid >> 2;          // 0..63
    const int nq  = (tid & 3) * 4;     // 0,4,8,12
#pragma unroll
    for (int p = 0; p < 8; p++) {
        const int c = p * 64 + sc_;
        floatx4 xv = *(const floatx4*)(xb + (size_t)c * 4096 + n0 + nq);
#pragma unroll
        for (int u = 0; u < 4; u++) xT[(nq + u) * 520 + c] = f2bf(xv[u]);
    }
    __syncthreads();

#pragma unroll 1
    for (int ot = 0; ot < 9; ot++) {
        floatx4 acc = (floatx4)(0.0f);
#pragma unroll 4
        for (int c0 = 0; c0 < 512; c0 += 32) {
            short8 af = *(const short8*)(wb + ((size_t)(ot * 16 + (c0 >> 5)) * 64
                                               + w * 16 + l15) * 32 + 8 * l4);
            short8 bf = *(const short8*)&xT[l15 * 520 + c0 + 8 * l4];
            acc = mfma16(af, bf, acc);
        }

#pragma unroll
        for (int r = 0; r < 4; r++) {
            const int o_d = ot * 64 + w * 16 + 4 * l4 + r;
            const int n = n0 + l15;
            const float val = acc[r];
            if (o_d < 32) {
                qT[((size_t)(b * 4096 + n)) * 32 + o_d] = f2bf(val + bq[o_d] * LOG2E);
            } else if (o_d < 64) {
                const int s = n & 31;
                const int p2 = 16 * ((s >> 2) & 1) + 4 * (s >> 3) + (s & 3);
                const int nst = (n & ~31) | p2;
                kT[((size_t)(b * 4096 + nst)) * 32 + (o_d - 32)] = f2bf(val + bk[o_d - 32]);
            } else {
                const int c = o_d - 64;
                vm[((size_t)((b * 128 + (n0 >> 5)) * 512 + c)) * 32
                   + (n & 31)] = f2bf(val + bv[c]);
            }
        }
    }
}

// ---------------- Flash attention + residual (R9 champion, verbatim) ----------------
// 256 blocks x 8 waves, QBLK=64, j-macro=256, dbuf P 64 KB, pipelined CONSUME
// (V triple-buffered, P double-buffered), setprio, tiled V loads (1KB contig).
__global__ __launch_bounds__(512, 1) void attn_kernel(
    const short* __restrict__ qT, const short* __restrict__ kT,
    const short* __restrict__ vm, const float* __restrict__ x,
    const float* __restrict__ gamma, float* __restrict__ out)
{
    __shared__ short P_lds[2][32 * 512];   // [buf][frag = w*4+it][lane*8]
    __shared__ float red_lds[8][64];
    const int tid = threadIdx.x;
    const int lane = tid & 63;
    const int w = tid >> 6;
    const int l15 = lane & 15, l4 = lane >> 4;

    const int bid = blockIdx.x;
    const int xcd = bid & 7;
    const int idx = bid >> 3;            // 0..31
    const int b   = xcd >> 1;
    const int qt  = (xcd & 1) * 32 + idx;
    const int i0  = qt * 64;
    const int cb  = w * 64;

    short8 qf[4];
#pragma unroll
    for (int it = 0; it < 4; it++)
        qf[it] = *(const short8*)(qT + ((size_t)(b * 4096 + i0 + it * 16 + l15)) * 32 + 8 * l4);

    floatx4 acc[4][4];   // [ct][it]
#pragma unroll
    for (int ct = 0; ct < 4; ct++)
#pragma unroll
        for (int it = 0; it < 4; it++) acc[ct][it] = (floatx4)(0.0f);

    float l_[4] = {0.0f, 0.0f, 0.0f, 0.0f};

    const short* kb = kT + (size_t)b * 4096 * 32;
    const short* vb = vm + (size_t)b * 512 * 4096;   // tiled [jt][512][32]

#define PROD(T, KF0, KF1)                                                            \
    {                                                                                \
        const int buf = (T) & 1;                                                     \
        _Pragma("unroll")                                                            \
        for (int it = 0; it < 4; it++) {                                             \
            floatx4 s0 = mfma16((KF0), qf[it], (floatx4)(0.0f));                     \
            floatx4 s1 = mfma16((KF1), qf[it], (floatx4)(0.0f));                     \
            float p[8];                                                              \
            _Pragma("unroll")                                                        \
            for (int r = 0; r < 4; r++) {                                            \
                p[r]     = __builtin_amdgcn_exp2f(s0[r]);                            \
                p[4 + r] = __builtin_amdgcn_exp2f(s1[r]);                            \
            }                                                                        \
            union { short8 s; unsigned u[4]; } pk;                                   \
            _Pragma("unroll")                                                        \
            for (int j2 = 0; j2 < 4; j2++) pk.u[j2] = cvt_pk_bf16(p[2*j2], p[2*j2+1]); \
            *(short8*)&P_lds[buf][(w * 4 + it) * 512 + lane * 8] = pk.s;             \
            l_[it] += ((p[0] + p[1]) + (p[2] + p[3])) + ((p[4] + p[5]) + (p[6] + p[7])); \
        }                                                                            \
    }

#define VLOAD(T, JG, CT)                                                             \
    (*(const short8*)(vb + ((size_t)(((T) * 8 + (JG)) * 512 + cb + (CT) * 16 + l15)) * 32 + 8 * l4))
#define PREAD(BUF, JG, IT)                                                           \
    (*(const short8*)&P_lds[BUF][((JG) * 4 + (IT)) * 512 + lane * 8])

#define CONSUME(T)                                                                   \
    {                                                                                \
        const int buf = (T) & 1;                                                     \
        short8 vfp[3][4];                                                            \
        short8 pcp[2][4];                                                            \
        _Pragma("unroll")                                                            \
        for (int ct = 0; ct < 4; ct++) vfp[0][ct] = VLOAD(T, 0, ct);                 \
        _Pragma("unroll")                                                            \
        for (int ct = 0; ct < 4; ct++) vfp[1][ct] = VLOAD(T, 1, ct);                 \
        _Pragma("unroll")                                                            \
        for (int it = 0; it < 4; it++) pcp[0][it] = PREAD(buf, 0, it);               \
        _Pragma("unroll")                                                            \
        for (int jg = 0; jg < 8; jg++) {                                             \
            if (jg < 6) {                                                            \
                _Pragma("unroll")                                                    \
                for (int ct = 0; ct < 4; ct++)                                       \
                    vfp[(jg + 2) % 3][ct] = VLOAD(T, jg + 2, ct);                    \
            }                                                                        \
            if (jg < 7) {                                                            \
                _Pragma("unroll")                                                    \
                for (int it = 0; it < 4; it++)                                       \
                    pcp[(jg + 1) & 1][it] = PREAD(buf, jg + 1, it);                  \
            }                                                                        \
            __builtin_amdgcn_s_setprio(1);                                           \
            _Pragma("unroll")                                                        \
            for (int ct = 0; ct < 4; ct++)                                           \
                _Pragma("unroll")                                                    \
                for (int it = 0; it < 4; it++)                                       \
                    acc[ct][it] = mfma16(vfp[jg % 3][ct], pcp[jg & 1][it], acc[ct][it]); \
            __builtin_amdgcn_s_setprio(0);                                           \
        }                                                                            \
    }

    // prologue: produce macro-tile 0
    {
        short8 kf0 = *(const short8*)(kb + (size_t)(w * 32 + l15) * 32 + 8 * l4);
        short8 kf1 = *(const short8*)(kb + (size_t)(w * 32 + 16 + l15) * 32 + 8 * l4);
        PROD(0, kf0, kf1);
    }

#pragma unroll 1
    for (int t = 0; t < 16; t++) {
        __syncthreads();
        short8 nk0, nk1;
        if (t < 15) {   // hoist next K loads; latency hides under CONSUME
            const int jj = (t + 1) * 256 + w * 32;
            nk0 = *(const short8*)(kb + (size_t)(jj + l15) * 32 + 8 * l4);
            nk1 = *(const short8*)(kb + (size_t)(jj + 16 + l15) * 32 + 8 * l4);
        }
        CONSUME(t);
        if (t < 15) PROD(t + 1, nk0, nk1);
    }
#undef PROD
#undef CONSUME
#undef VLOAD
#undef PREAD

    // l: reduce within wave, then across 8 waves via LDS
#pragma unroll
    for (int it = 0; it < 4; it++) {
        l_[it] += __shfl_xor(l_[it], 16, 64);
        l_[it] += __shfl_xor(l_[it], 32, 64);
    }
    if (lane < 16)
#pragma unroll
        for (int it = 0; it < 4; it++) red_lds[w][it * 16 + lane] = l_[it];
    __syncthreads();

    const float g = gamma[0];
    float inv[4];
#pragma unroll
    for (int it = 0; it < 4; it++) {
        float s = 0.0f;
#pragma unroll
        for (int ww = 0; ww < 8; ww++) s += red_lds[ww][it * 16 + l15];
        inv[it] = g / s;
    }

#pragma unroll
    for (int ct = 0; ct < 4; ct++)
#pragma unroll
        for (int it = 0; it < 4; it++)
#pragma unroll
            for (int r = 0; r < 4; r++) {
                const int c = cb + ct * 16 + 4 * l4 + r;
                const int i = i0 + it * 16 + l15;
                const size_t o = ((size_t)(b * 512 + c)) * 4096 + i;
                out[o] = acc[ct][it][r] * inv[it] + x[o];
            }
}

extern "C" void kernel_launch(void* const* d_in, const int* in_sizes, int n_in,
                              void* d_out, int out_size, void* d_ws, size_t ws_size,
                              hipStream_t stream) {
    const float* x     = (const float*)d_in[0];
    const float* wq    = (const float*)d_in[1];
    const float* bq    = (const float*)d_in[2];
    const float* wk    = (const float*)d_in[3];
    const float* bk    = (const float*)d_in[4];
    const float* wv    = (const float*)d_in[5];
    const float* bv    = (const float*)d_in[6];
    const float* gamma = (const float*)d_in[7];
    float* out = (float*)d_out;

    short* qT = (short*)d_ws;                  // 1 MB
    short* kT = qT + (size_t)4 * 4096 * 32;    // 1 MB
    short* vm = kT + (size_t)4 * 4096 * 32;    // 16 MB (tiled [b][jt][512][32])
    short* wb = vm + (size_t)4 * 512 * 4096;   // 0.56 MB (tiled)

    wcvt_kernel<<<288, 256, 0, stream>>>(wq, wk, wv, wb);
    proj_kernel<<<dim3(256, 4), 256, 0, stream>>>(x, wb, bq, bk, bv, qT, kT, vm);
    attn_kernel<<<256, 512, 0, stream>>>(qT, kT, vm, x, gamma, out);
}

// Round 14
// 138.196 us; speedup vs baseline: 1.1762x; 1.0747x over previous
//
#include <hip/hip_runtime.h>
#include <hip/hip_bf16.h>

#define LOG2E 1.44269504088896340736f

typedef __attribute__((ext_vector_type(8))) short short8;
typedef __attribute__((ext_vector_type(4))) float floatx4;

static __device__ __forceinline__ short f2bf(float f) {
    union { float f; unsigned u; } v; v.f = f;
    unsigned r = (v.u + 0x7FFF + ((v.u >> 16) & 1)) >> 16;  // RNE
    return (short)r;
}

static __device__ __forceinline__ floatx4 mfma16(short8 a, short8 b, floatx4 c) {
    return __builtin_amdgcn_mfma_f32_16x16x32_bf16(a, b, c, 0, 0, 0);
}

static __device__ __forceinline__ unsigned cvt_pk_bf16(float lo, float hi) {
    unsigned u;
    asm("v_cvt_pk_bf16_f32 %0, %1, %2" : "=v"(u) : "v"(lo), "v"(hi));
    return u;
}

// ---------------- Weight pre-convert: wb tiled [(ot*16+cg)][64 o][32 c] ----------------
__global__ __launch_bounds__(256) void wcvt_kernel(
    const float* __restrict__ wq, const float* __restrict__ wk,
    const float* __restrict__ wv, short* __restrict__ wb)
{
    const int idx = (blockIdx.x * 256 + threadIdx.x) * 4;   // 294912 total
    const int row = idx >> 9;          // 0..575
    const int col = idx & 511;
    const float* src;
    float sc = 1.0f;
    if (row < 32)      { src = wq + (size_t)row * 512; sc = LOG2E; }
    else if (row < 64) { src = wk + (size_t)(row - 32) * 512; }
    else               { src = wv + (size_t)(row - 64) * 512; }
    floatx4 v = *(const floatx4*)(src + col);
    union { short s[4]; long long ll; } o;
#pragma unroll
    for (int u = 0; u < 4; u++) o.s[u] = f2bf(v[u] * sc);
    const int didx = (((row >> 6) * 16 + (col >> 5)) * 64 + (row & 63)) * 32 + (col & 31);
    *(long long*)(wb + didx) = o.ll;
}

// ---------------- Projection (R9 version, measured best) ----------------
// grid (128 n-tiles of 32, B), block 256 (4 waves). x read once; W contiguous.
__global__ __launch_bounds__(256) void proj_kernel(
    const float* __restrict__ x, const short* __restrict__ wb,
    const float* __restrict__ bq, const float* __restrict__ bk,
    const float* __restrict__ bv,
    short* __restrict__ qT, short* __restrict__ kT, short* __restrict__ vm)
{
    __shared__ short xT[32 * 520];   // [n][c] bf16, pitch 520
    const int tid = threadIdx.x;
    const int w = tid >> 6;
    const int lane = tid & 63;
    const int l15 = lane & 15, l4 = lane >> 4;
    const int n0 = blockIdx.x * 32;
    const int b  = blockIdx.y;

    const float* xb = x + (size_t)b * 512 * 4096;

    const int cp = tid >> 3;          // 0..31
    const int nq = (tid & 7) * 4;     // 0,4,..,28
#pragma unroll
    for (int p = 0; p < 8; p++) {
        const int c = (p * 32 + cp) * 2;
        const float* r0 = xb + (size_t)c * 4096 + n0 + nq;
        const float* r1 = r0 + 4096;
        floatx4 xa = *(const floatx4*)r0;
        floatx4 xc = *(const floatx4*)r1;
#pragma unroll
        for (int u = 0; u < 4; u++)
            *(unsigned*)&xT[(nq + u) * 520 + c] = cvt_pk_bf16(xa[u], xc[u]);
    }
    __syncthreads();

#pragma unroll 1
    for (int ot = 0; ot < 9; ot++) {
        floatx4 acc[2];
#pragma unroll
        for (int i = 0; i < 2; i++) acc[i] = (floatx4)(0.0f);

#pragma unroll 4
        for (int c0 = 0; c0 < 512; c0 += 32) {
            short8 af = *(const short8*)(wb + ((size_t)(ot * 16 + (c0 >> 5)) * 64
                                               + w * 16 + l15) * 32 + 8 * l4);
#pragma unroll
            for (int nt = 0; nt < 2; nt++) {
                short8 bf = *(const short8*)&xT[(nt * 16 + l15) * 520 + c0 + 8 * l4];
                acc[nt] = mfma16(af, bf, acc[nt]);
            }
        }

#pragma unroll
        for (int r = 0; r < 4; r++) {
            const int o_d = ot * 64 + w * 16 + 4 * l4 + r;
#pragma unroll
            for (int nt = 0; nt < 2; nt++) {
                const int n = n0 + nt * 16 + l15;
                const float val = acc[nt][r];
                if (o_d < 32) {
                    qT[((size_t)(b * 4096 + n)) * 32 + o_d] = f2bf(val + bq[o_d] * LOG2E);
                } else if (o_d < 64) {
                    const int s = n & 31;
                    const int p2 = 16 * ((s >> 2) & 1) + 4 * (s >> 3) + (s & 3);
                    const int nst = (n & ~31) | p2;
                    kT[((size_t)(b * 4096 + nst)) * 32 + (o_d - 32)] = f2bf(val + bk[o_d - 32]);
                } else {
                    const int c = o_d - 64;
                    vm[((size_t)((b * 128 + blockIdx.x) * 512 + c)) * 32
                       + (nt * 16 + l15)] = f2bf(val + bv[c]);
                }
            }
        }
    }
}

// ---------------- Flash attention + residual ----------------
// 256 blocks x 8 waves, QBLK=64. j-macro = 128 with 16-j production slices:
// wave w produces P for stored K rows [t*128 + w*16, +16) (1 K load, 4 QK MFMA,
// 16 exp2/lane), writes 8B frags. Consumer chunk jc combines slices 2jc,2jc+1
// (two b64 reads = one B-fragment; K-perm algebra verified). P_lds 2x16 KB ->
// total LDS 34 KB -> 2 blocks/CU co-residency at VGPR<=128. Density per V-load
// unchanged (4 MFMA). Tiled V (contiguous 1KB loads).
__global__ __launch_bounds__(512, 1) void attn_kernel(
    const short* __restrict__ qT, const short* __restrict__ kT,
    const short* __restrict__ vm, const float* __restrict__ x,
    const float* __restrict__ gamma, float* __restrict__ out)
{
    __shared__ short P_lds[2][32 * 256];   // [buf][(slice*4+it)*256 + lane*4]
    __shared__ float red_lds[8][64];
    const int tid = threadIdx.x;
    const int lane = tid & 63;
    const int w = tid >> 6;
    const int l15 = lane & 15, l4 = lane >> 4;

    const int bid = blockIdx.x;
    const int xcd = bid & 7;
    const int idx = bid >> 3;            // 0..31
    const int b   = xcd >> 1;
    const int qt  = (xcd & 1) * 32 + idx;
    const int i0  = qt * 64;
    const int cb  = w * 64;

    short8 qf[4];
#pragma unroll
    for (int it = 0; it < 4; it++)
        qf[it] = *(const short8*)(qT + ((size_t)(b * 4096 + i0 + it * 16 + l15)) * 32 + 8 * l4);

    floatx4 acc[4][4];   // [ct][it]
#pragma unroll
    for (int ct = 0; ct < 4; ct++)
#pragma unroll
        for (int it = 0; it < 4; it++) acc[ct][it] = (floatx4)(0.0f);

    float l_[4] = {0.0f, 0.0f, 0.0f, 0.0f};

    const short* kb = kT + (size_t)b * 4096 * 32;
    const short* vb = vm + (size_t)b * 512 * 4096;   // tiled [jt][512][32]

#define KLOAD(T)  (*(const short8*)(kb + (size_t)((T) * 128 + w * 16 + l15) * 32 + 8 * l4))

#define PROD(T, KF)                                                                  \
    {                                                                                \
        const int buf = (T) & 1;                                                     \
        _Pragma("unroll")                                                            \
        for (int it = 0; it < 4; it++) {                                             \
            floatx4 s0 = mfma16((KF), qf[it], (floatx4)(0.0f));                      \
            float p0 = __builtin_amdgcn_exp2f(s0[0]);                                \
            float p1 = __builtin_amdgcn_exp2f(s0[1]);                                \
            float p2 = __builtin_amdgcn_exp2f(s0[2]);                                \
            float p3 = __builtin_amdgcn_exp2f(s0[3]);                                \
            union { long long ll; unsigned u[2]; } pk;                               \
            pk.u[0] = cvt_pk_bf16(p0, p1);                                           \
            pk.u[1] = cvt_pk_bf16(p2, p3);                                           \
            *(long long*)&P_lds[buf][(w * 4 + it) * 256 + lane * 4] = pk.ll;         \
            l_[it] += (p0 + p1) + (p2 + p3);                                         \
        }                                                                            \
    }

#define VLOAD(T, JC, CT)                                                             \
    (*(const short8*)(vb + ((size_t)(((T) * 4 + (JC)) * 512 + cb + (CT) * 16 + l15)) * 32 + 8 * l4))

#define PFRAG(BUF, JC, IT, DST)                                                      \
    {                                                                                \
        union { short8 s; long long d[2]; } _pf;                                     \
        _pf.d[0] = *(const long long*)&P_lds[BUF][((2 * (JC)) * 4 + (IT)) * 256 + lane * 4];     \
        _pf.d[1] = *(const long long*)&P_lds[BUF][((2 * (JC) + 1) * 4 + (IT)) * 256 + lane * 4]; \
        DST = _pf.s;                                                                 \
    }

#define CONSUME(T)                                                                   \
    {                                                                                \
        const int buf = (T) & 1;                                                     \
        short8 vfp[2][4];                                                            \
        short8 pcp[2][4];                                                            \
        _Pragma("unroll")                                                            \
        for (int ct = 0; ct < 4; ct++) vfp[0][ct] = VLOAD(T, 0, ct);                 \
        _Pragma("unroll")                                                            \
        for (int it = 0; it < 4; it++) PFRAG(buf, 0, it, pcp[0][it]);                \
        _Pragma("unroll")                                                            \
        for (int jc = 0; jc < 4; jc++) {                                             \
            if (jc < 3) {                                                            \
                _Pragma("unroll")                                                    \
                for (int ct = 0; ct < 4; ct++) vfp[(jc + 1) & 1][ct] = VLOAD(T, jc + 1, ct); \
                _Pragma("unroll")                                                    \
                for (int it = 0; it < 4; it++) PFRAG(buf, jc + 1, it, pcp[(jc + 1) & 1][it]); \
            }                                                                        \
            __builtin_amdgcn_s_setprio(1);                                           \
            _Pragma("unroll")                                                        \
            for (int ct = 0; ct < 4; ct++)                                           \
                _Pragma("unroll")                                                    \
                for (int it = 0; it < 4; it++)                                       \
                    acc[ct][it] = mfma16(vfp[jc & 1][ct], pcp[jc & 1][it], acc[ct][it]); \
            __builtin_amdgcn_s_setprio(0);                                           \
        }                                                                            \
    }

    // prologue: produce macro-tile 0
    {
        short8 kf = KLOAD(0);
        PROD(0, kf);
    }

#pragma unroll 1
    for (int t = 0; t < 32; t++) {
        __syncthreads();
        short8 nk;
        if (t < 31) nk = KLOAD(t + 1);   // latency hides under CONSUME
        CONSUME(t);
        if (t < 31) PROD(t + 1, nk);
    }
#undef KLOAD
#undef PROD
#undef VLOAD
#undef PFRAG
#undef CONSUME

    // l: reduce within wave, then across 8 waves via LDS
#pragma unroll
    for (int it = 0; it < 4; it++) {
        l_[it] += __shfl_xor(l_[it], 16, 64);
        l_[it] += __shfl_xor(l_[it], 32, 64);
    }
    if (lane < 16)
#pragma unroll
        for (int it = 0; it < 4; it++) red_lds[w][it * 16 + lane] = l_[it];
    __syncthreads();

    const float g = gamma[0];
    float inv[4];
#pragma unroll
    for (int it = 0; it < 4; it++) {
        float s = 0.0f;
#pragma unroll
        for (int ww = 0; ww < 8; ww++) s += red_lds[ww][it * 16 + l15];
        inv[it] = g / s;
    }

#pragma unroll
    for (int ct = 0; ct < 4; ct++)
#pragma unroll
        for (int it = 0; it < 4; it++)
#pragma unroll
            for (int r = 0; r < 4; r++) {
                const int c = cb + ct * 16 + 4 * l4 + r;
                const int i = i0 + it * 16 + l15;
                const size_t o = ((size_t)(b * 512 + c)) * 4096 + i;
                out[o] = acc[ct][it][r] * inv[it] + x[o];
            }
}

extern "C" void kernel_launch(void* const* d_in, const int* in_sizes, int n_in,
                              void* d_out, int out_size, void* d_ws, size_t ws_size,
                              hipStream_t stream) {
    const float* x     = (const float*)d_in[0];
    const float* wq    = (const float*)d_in[1];
    const float* bq    = (const float*)d_in[2];
    const float* wk    = (const float*)d_in[3];
    const float* bk    = (const float*)d_in[4];
    const float* wv    = (const float*)d_in[5];
    const float* bv    = (const float*)d_in[6];
    const float* gamma = (const float*)d_in[7];
    float* out = (float*)d_out;

    short* qT = (short*)d_ws;                  // 1 MB
    short* kT = qT + (size_t)4 * 4096 * 32;    // 1 MB
    short* vm = kT + (size_t)4 * 4096 * 32;    // 16 MB (tiled [b][jt][512][32])
    short* wb = vm + (size_t)4 * 512 * 4096;   // 0.56 MB (tiled)

    wcvt_kernel<<<288, 256, 0, stream>>>(wq, wk, wv, wb);
    proj_kernel<<<dim3(128, 4), 256, 0, stream>>>(x, wb, bq, bk, bv, qT, kT, vm);
    attn_kernel<<<256, 512, 0, stream>>>(qT, kT, vm, x, gamma, out);
}

// Round 15
// 126.051 us; speedup vs baseline: 1.2896x; 1.0963x over previous
//
#include <hip/hip_runtime.h>
#include <hip/hip_bf16.h>

#define LOG2E 1.44269504088896340736f

typedef __attribute__((ext_vector_type(8))) short short8;
typedef __attribute__((ext_vector_type(4))) float floatx4;

static __device__ __forceinline__ short f2bf(float f) {
    union { float f; unsigned u; } v; v.f = f;
    unsigned r = (v.u + 0x7FFF + ((v.u >> 16) & 1)) >> 16;  // RNE
    return (short)r;
}

static __device__ __forceinline__ floatx4 mfma16(short8 a, short8 b, floatx4 c) {
    return __builtin_amdgcn_mfma_f32_16x16x32_bf16(a, b, c, 0, 0, 0);
}

static __device__ __forceinline__ unsigned cvt_pk_bf16(float lo, float hi) {
    unsigned u;
    asm("v_cvt_pk_bf16_f32 %0, %1, %2" : "=v"(u) : "v"(lo), "v"(hi));
    return u;
}

// ---------------- Weight pre-convert: wb tiled [(ot*16+cg)][64 o][32 c] ----------------
__global__ __launch_bounds__(256) void wcvt_kernel(
    const float* __restrict__ wq, const float* __restrict__ wk,
    const float* __restrict__ wv, short* __restrict__ wb)
{
    const int idx = (blockIdx.x * 256 + threadIdx.x) * 4;   // 294912 total
    const int row = idx >> 9;          // 0..575
    const int col = idx & 511;
    const float* src;
    float sc = 1.0f;
    if (row < 32)      { src = wq + (size_t)row * 512; sc = LOG2E; }
    else if (row < 64) { src = wk + (size_t)(row - 32) * 512; }
    else               { src = wv + (size_t)(row - 64) * 512; }
    floatx4 v = *(const floatx4*)(src + col);
    union { short s[4]; long long ll; } o;
#pragma unroll
    for (int u = 0; u < 4; u++) o.s[u] = f2bf(v[u] * sc);
    const int didx = (((row >> 6) * 16 + (col >> 5)) * 64 + (row & 63)) * 32 + (col & 31);
    *(long long*)(wb + didx) = o.ll;
}

// ---------------- Projection: swapped-operand MFMA -> wide v-stores ----------------
// grid (128 n-tiles of 32, B), block 256 (4 waves). x read once; W contiguous.
// mfma16(xf, wf): D[l15 -> o][4*l4+r -> n], so each thread holds 4 consecutive n
// for one channel -> v-stores are b64 (2x cvt_pk). q/k (1/9 of work) stay scalar.
__global__ __launch_bounds__(256) void proj_kernel(
    const float* __restrict__ x, const short* __restrict__ wb,
    const float* __restrict__ bq, const float* __restrict__ bk,
    const float* __restrict__ bv,
    short* __restrict__ qT, short* __restrict__ kT, short* __restrict__ vm)
{
    __shared__ short xT[32 * 520];   // [n][c] bf16, pitch 520
    const int tid = threadIdx.x;
    const int w = tid >> 6;
    const int lane = tid & 63;
    const int l15 = lane & 15, l4 = lane >> 4;
    const int n0 = blockIdx.x * 32;
    const int b  = blockIdx.y;

    const float* xb = x + (size_t)b * 512 * 4096;

    const int cp = tid >> 3;          // 0..31
    const int nq = (tid & 7) * 4;     // 0,4,..,28
#pragma unroll
    for (int p = 0; p < 8; p++) {
        const int c = (p * 32 + cp) * 2;
        const float* r0 = xb + (size_t)c * 4096 + n0 + nq;
        const float* r1 = r0 + 4096;
        floatx4 xa = *(const floatx4*)r0;
        floatx4 xc = *(const floatx4*)r1;
#pragma unroll
        for (int u = 0; u < 4; u++)
            *(unsigned*)&xT[(nq + u) * 520 + c] = cvt_pk_bf16(xa[u], xc[u]);
    }
    __syncthreads();

#pragma unroll 1
    for (int ot = 0; ot < 9; ot++) {
        floatx4 acc[2];
#pragma unroll
        for (int i = 0; i < 2; i++) acc[i] = (floatx4)(0.0f);

#pragma unroll 4
        for (int c0 = 0; c0 < 512; c0 += 32) {
            short8 wf = *(const short8*)(wb + ((size_t)(ot * 16 + (c0 >> 5)) * 64
                                               + w * 16 + l15) * 32 + 8 * l4);
#pragma unroll
            for (int nt = 0; nt < 2; nt++) {
                short8 xf = *(const short8*)&xT[(nt * 16 + l15) * 520 + c0 + 8 * l4];
                acc[nt] = mfma16(xf, wf, acc[nt]);   // swapped: D[l15->o][4l4+r->n]
            }
        }

        const int o_d = ot * 64 + w * 16 + l15;
        if (o_d < 32) {
            const float bqe = bq[o_d] * LOG2E;
#pragma unroll
            for (int nt = 0; nt < 2; nt++)
#pragma unroll
                for (int r = 0; r < 4; r++) {
                    const int n = n0 + nt * 16 + 4 * l4 + r;
                    qT[((size_t)(b * 4096 + n)) * 32 + o_d] = f2bf(acc[nt][r] + bqe);
                }
        } else if (o_d < 64) {
            const float bke = bk[o_d - 32];
#pragma unroll
            for (int nt = 0; nt < 2; nt++)
#pragma unroll
                for (int r = 0; r < 4; r++) {
                    const int n = n0 + nt * 16 + 4 * l4 + r;
                    const int s = n & 31;
                    const int p2 = 16 * ((s >> 2) & 1) + 4 * (s >> 3) + (s & 3);
                    const int nst = (n & ~31) | p2;
                    kT[((size_t)(b * 4096 + nst)) * 32 + (o_d - 32)] = f2bf(acc[nt][r] + bke);
                }
        } else {
            const int c = o_d - 64;
            const float bvc = bv[c];
            short* dst = vm + ((size_t)((b * 128 + blockIdx.x) * 512 + c)) * 32;
#pragma unroll
            for (int nt = 0; nt < 2; nt++) {
                union { long long ll; unsigned u2[2]; } pk;
                pk.u2[0] = cvt_pk_bf16(acc[nt][0] + bvc, acc[nt][1] + bvc);
                pk.u2[1] = cvt_pk_bf16(acc[nt][2] + bvc, acc[nt][3] + bvc);
                *(long long*)(dst + nt * 16 + 4 * l4) = pk.ll;
            }
        }
    }
}

// ---------------- Flash attention + residual (R9 champion, verbatim) ----------------
// 256 blocks x 8 waves, QBLK=64, j-macro=256, dbuf P 64 KB, pipelined CONSUME
// (V triple-buffered, P double-buffered), setprio, tiled V loads (1KB contig).
__global__ __launch_bounds__(512, 1) void attn_kernel(
    const short* __restrict__ qT, const short* __restrict__ kT,
    const short* __restrict__ vm, const float* __restrict__ x,
    const float* __restrict__ gamma, float* __restrict__ out)
{
    __shared__ short P_lds[2][32 * 512];   // [buf][frag = w*4+it][lane*8]
    __shared__ float red_lds[8][64];
    const int tid = threadIdx.x;
    const int lane = tid & 63;
    const int w = tid >> 6;
    const int l15 = lane & 15, l4 = lane >> 4;

    const int bid = blockIdx.x;
    const int xcd = bid & 7;
    const int idx = bid >> 3;            // 0..31
    const int b   = xcd >> 1;
    const int qt  = (xcd & 1) * 32 + idx;
    const int i0  = qt * 64;
    const int cb  = w * 64;

    short8 qf[4];
#pragma unroll
    for (int it = 0; it < 4; it++)
        qf[it] = *(const short8*)(qT + ((size_t)(b * 4096 + i0 + it * 16 + l15)) * 32 + 8 * l4);

    floatx4 acc[4][4];   // [ct][it]
#pragma unroll
    for (int ct = 0; ct < 4; ct++)
#pragma unroll
        for (int it = 0; it < 4; it++) acc[ct][it] = (floatx4)(0.0f);

    float l_[4] = {0.0f, 0.0f, 0.0f, 0.0f};

    const short* kb = kT + (size_t)b * 4096 * 32;
    const short* vb = vm + (size_t)b * 512 * 4096;   // tiled [jt][512][32]

#define PROD(T, KF0, KF1)                                                            \
    {                                                                                \
        const int buf = (T) & 1;                                                     \
        _Pragma("unroll")                                                            \
        for (int it = 0; it < 4; it++) {                                             \
            floatx4 s0 = mfma16((KF0), qf[it], (floatx4)(0.0f));                     \
            floatx4 s1 = mfma16((KF1), qf[it], (floatx4)(0.0f));                     \
            float p[8];                                                              \
            _Pragma("unroll")                                                        \
            for (int r = 0; r < 4; r++) {                                            \
                p[r]     = __builtin_amdgcn_exp2f(s0[r]);                            \
                p[4 + r] = __builtin_amdgcn_exp2f(s1[r]);                            \
            }                                                                        \
            union { short8 s; unsigned u[4]; } pk;                                   \
            _Pragma("unroll")                                                        \
            for (int j2 = 0; j2 < 4; j2++) pk.u[j2] = cvt_pk_bf16(p[2*j2], p[2*j2+1]); \
            *(short8*)&P_lds[buf][(w * 4 + it) * 512 + lane * 8] = pk.s;             \
            l_[it] += ((p[0] + p[1]) + (p[2] + p[3])) + ((p[4] + p[5]) + (p[6] + p[7])); \
        }                                                                            \
    }

#define VLOAD(T, JG, CT)                                                             \
    (*(const short8*)(vb + ((size_t)(((T) * 8 + (JG)) * 512 + cb + (CT) * 16 + l15)) * 32 + 8 * l4))
#define PREAD(BUF, JG, IT)                                                           \
    (*(const short8*)&P_lds[BUF][((JG) * 4 + (IT)) * 512 + lane * 8])

#define CONSUME(T)                                                                   \
    {                                                                                \
        const int buf = (T) & 1;                                                     \
        short8 vfp[3][4];                                                            \
        short8 pcp[2][4];                                                            \
        _Pragma("unroll")                                                            \
        for (int ct = 0; ct < 4; ct++) vfp[0][ct] = VLOAD(T, 0, ct);                 \
        _Pragma("unroll")                                                            \
        for (int ct = 0; ct < 4; ct++) vfp[1][ct] = VLOAD(T, 1, ct);                 \
        _Pragma("unroll")                                                            \
        for (int it = 0; it < 4; it++) pcp[0][it] = PREAD(buf, 0, it);               \
        _Pragma("unroll")                                                            \
        for (int jg = 0; jg < 8; jg++) {                                             \
            if (jg < 6) {                                                            \
                _Pragma("unroll")                                                    \
                for (int ct = 0; ct < 4; ct++)                                       \
                    vfp[(jg + 2) % 3][ct] = VLOAD(T, jg + 2, ct);                    \
            }                                                                        \
            if (jg < 7) {                                                            \
                _Pragma("unroll")                                                    \
                for (int it = 0; it < 4; it++)                                       \
                    pcp[(jg + 1) & 1][it] = PREAD(buf, jg + 1, it);                  \
            }                                                                        \
            __builtin_amdgcn_s_setprio(1);                                           \
            _Pragma("unroll")                                                        \
            for (int ct = 0; ct < 4; ct++)                                           \
                _Pragma("unroll")                                                    \
                for (int it = 0; it < 4; it++)                                       \
                    acc[ct][it] = mfma16(vfp[jg % 3][ct], pcp[jg & 1][it], acc[ct][it]); \
            __builtin_amdgcn_s_setprio(0);                                           \
        }                                                                            \
    }

    // prologue: produce macro-tile 0
    {
        short8 kf0 = *(const short8*)(kb + (size_t)(w * 32 + l15) * 32 + 8 * l4);
        short8 kf1 = *(const short8*)(kb + (size_t)(w * 32 + 16 + l15) * 32 + 8 * l4);
        PROD(0, kf0, kf1);
    }

#pragma unroll 1
    for (int t = 0; t < 16; t++) {
        __syncthreads();
        short8 nk0, nk1;
        if (t < 15) {   // hoist next K loads; latency hides under CONSUME
            const int jj = (t + 1) * 256 + w * 32;
            nk0 = *(const short8*)(kb + (size_t)(jj + l15) * 32 + 8 * l4);
            nk1 = *(const short8*)(kb + (size_t)(jj + 16 + l15) * 32 + 8 * l4);
        }
        CONSUME(t);
        if (t < 15) PROD(t + 1, nk0, nk1);
    }
#undef PROD
#undef CONSUME
#undef VLOAD
#undef PREAD

    // l: reduce within wave, then across 8 waves via LDS
#pragma unroll
    for (int it = 0; it < 4; it++) {
        l_[it] += __shfl_xor(l_[it], 16, 64);
        l_[it] += __shfl_xor(l_[it], 32, 64);
    }
    if (lane < 16)
#pragma unroll
        for (int it = 0; it < 4; it++) red_lds[w][it * 16 + lane] = l_[it];
    __syncthreads();

    const float g = gamma[0];
    float inv[4];
#pragma unroll
    for (int it = 0; it < 4; it++) {
        float s = 0.0f;
#pragma unroll
        for (int ww = 0; ww < 8; ww++) s += red_lds[ww][it * 16 + l15];
        inv[it] = g / s;
    }

#pragma unroll
    for (int ct = 0; ct < 4; ct++)
#pragma unroll
        for (int it = 0; it < 4; it++)
#pragma unroll
            for (int r = 0; r < 4; r++) {
                const int c = cb + ct * 16 + 4 * l4 + r;
                const int i = i0 + it * 16 + l15;
                const size_t o = ((size_t)(b * 512 + c)) * 4096 + i;
                out[o] = acc[ct][it][r] * inv[it] + x[o];
            }
}

extern "C" void kernel_launch(void* const* d_in, const int* in_sizes, int n_in,
                              void* d_out, int out_size, void* d_ws, size_t ws_size,
                              hipStream_t stream) {
    const float* x     = (const float*)d_in[0];
    const float* wq    = (const float*)d_in[1];
    const float* bq    = (const float*)d_in[2];
    const float* wk    = (const float*)d_in[3];
    const float* bk    = (const float*)d_in[4];
    const float* wv    = (const float*)d_in[5];
    const float* bv    = (const float*)d_in[6];
    const float* gamma = (const float*)d_in[7];
    float* out = (float*)d_out;

    short* qT = (short*)d_ws;                  // 1 MB
    short* kT = qT + (size_t)4 * 4096 * 32;    // 1 MB
    short* vm = kT + (size_t)4 * 4096 * 32;    // 16 MB (tiled [b][jt][512][32])
    short* wb = vm + (size_t)4 * 512 * 4096;   // 0.56 MB (tiled)

    wcvt_kernel<<<288, 256, 0, stream>>>(wq, wk, wv, wb);
    proj_kernel<<<dim3(128, 4), 256, 0, stream>>>(x, wb, bq, bk, bv, qT, kT, vm);
    attn_kernel<<<256, 512, 0, stream>>>(qT, kT, vm, x, gamma, out);
}

// Round 16
// 121.838 us; speedup vs baseline: 1.3341x; 1.0346x over previous
//
#include <hip/hip_runtime.h>
#include <hip/hip_bf16.h>

#define LOG2E 1.44269504088896340736f

typedef __attribute__((ext_vector_type(8))) short short8;
typedef __attribute__((ext_vector_type(4))) float floatx4;

static __device__ __forceinline__ short f2bf(float f) {
    union { float f; unsigned u; } v; v.f = f;
    unsigned r = (v.u + 0x7FFF + ((v.u >> 16) & 1)) >> 16;  // RNE
    return (short)r;
}

static __device__ __forceinline__ floatx4 mfma16(short8 a, short8 b, floatx4 c) {
    return __builtin_amdgcn_mfma_f32_16x16x32_bf16(a, b, c, 0, 0, 0);
}

static __device__ __forceinline__ unsigned cvt_pk_bf16(float lo, float hi) {
    unsigned u;
    asm("v_cvt_pk_bf16_f32 %0, %1, %2" : "=v"(u) : "v"(lo), "v"(hi));
    return u;
}

// ---------------- Weight pre-convert: wb tiled [(ot*16+cg)][64 o][32 c] ----------------
__global__ __launch_bounds__(256) void wcvt_kernel(
    const float* __restrict__ wq, const float* __restrict__ wk,
    const float* __restrict__ wv, short* __restrict__ wb)
{
    const int idx = (blockIdx.x * 256 + threadIdx.x) * 4;   // 294912 total
    const int row = idx >> 9;          // 0..575
    const int col = idx & 511;
    const float* src;
    float sc = 1.0f;
    if (row < 32)      { src = wq + (size_t)row * 512; sc = LOG2E; }
    else if (row < 64) { src = wk + (size_t)(row - 32) * 512; }
    else               { src = wv + (size_t)(row - 64) * 512; }
    floatx4 v = *(const floatx4*)(src + col);
    union { short s[4]; long long ll; } o;
#pragma unroll
    for (int u = 0; u < 4; u++) o.s[u] = f2bf(v[u] * sc);
    const int didx = (((row >> 6) * 16 + (col >> 5)) * 64 + (row & 63)) * 32 + (col & 31);
    *(long long*)(wb + didx) = o.ll;
}

// ---------------- Projection: ot-split for 4 blocks/CU ----------------
// grid (128 n-tiles of 32, 2 o-groups {0..4}/{5..8}, B), block 256 (4 waves),
// LDS 33 KB -> 4 blocks/CU (16 waves/CU). x staged twice (+32 MB, hidden).
// Swapped-operand MFMA: D[l15->o][4l4+r->n] -> b64 v-stores.
__global__ __launch_bounds__(256) void proj_kernel(
    const float* __restrict__ x, const short* __restrict__ wb,
    const float* __restrict__ bq, const float* __restrict__ bk,
    const float* __restrict__ bv,
    short* __restrict__ qT, short* __restrict__ kT, short* __restrict__ vm)
{
    __shared__ short xT[32 * 520];   // [n][c] bf16, pitch 520
    const int tid = threadIdx.x;
    const int w = tid >> 6;
    const int lane = tid & 63;
    const int l15 = lane & 15, l4 = lane >> 4;
    const int n0 = blockIdx.x * 32;
    const int og = blockIdx.y;       // 0: ot 0..4, 1: ot 5..8
    const int b  = blockIdx.z;

    const float* xb = x + (size_t)b * 512 * 4096;

    const int cp = tid >> 3;          // 0..31
    const int nq = (tid & 7) * 4;     // 0,4,..,28
#pragma unroll
    for (int p = 0; p < 8; p++) {
        const int c = (p * 32 + cp) * 2;
        const float* r0 = xb + (size_t)c * 4096 + n0 + nq;
        const float* r1 = r0 + 4096;
        floatx4 xa = *(const floatx4*)r0;
        floatx4 xc = *(const floatx4*)r1;
#pragma unroll
        for (int u = 0; u < 4; u++)
            *(unsigned*)&xT[(nq + u) * 520 + c] = cvt_pk_bf16(xa[u], xc[u]);
    }
    __syncthreads();

    const int ot_start = og * 5;          // 0 or 5
    const int ot_count = 5 - og;          // 5 or 4
#pragma unroll 1
    for (int oi = 0; oi < ot_count; oi++) {
        const int ot = ot_start + oi;
        floatx4 acc[2];
#pragma unroll
        for (int i = 0; i < 2; i++) acc[i] = (floatx4)(0.0f);

#pragma unroll 4
        for (int c0 = 0; c0 < 512; c0 += 32) {
            short8 wf = *(const short8*)(wb + ((size_t)(ot * 16 + (c0 >> 5)) * 64
                                               + w * 16 + l15) * 32 + 8 * l4);
#pragma unroll
            for (int nt = 0; nt < 2; nt++) {
                short8 xf = *(const short8*)&xT[(nt * 16 + l15) * 520 + c0 + 8 * l4];
                acc[nt] = mfma16(xf, wf, acc[nt]);   // swapped: D[l15->o][4l4+r->n]
            }
        }

        const int o_d = ot * 64 + w * 16 + l15;
        if (o_d < 32) {
            const float bqe = bq[o_d] * LOG2E;
#pragma unroll
            for (int nt = 0; nt < 2; nt++)
#pragma unroll
                for (int r = 0; r < 4; r++) {
                    const int n = n0 + nt * 16 + 4 * l4 + r;
                    qT[((size_t)(b * 4096 + n)) * 32 + o_d] = f2bf(acc[nt][r] + bqe);
                }
        } else if (o_d < 64) {
            const float bke = bk[o_d - 32];
#pragma unroll
            for (int nt = 0; nt < 2; nt++)
#pragma unroll
                for (int r = 0; r < 4; r++) {
                    const int n = n0 + nt * 16 + 4 * l4 + r;
                    const int s = n & 31;
                    const int p2 = 16 * ((s >> 2) & 1) + 4 * (s >> 3) + (s & 3);
                    const int nst = (n & ~31) | p2;
                    kT[((size_t)(b * 4096 + nst)) * 32 + (o_d - 32)] = f2bf(acc[nt][r] + bke);
                }
        } else {
            const int c = o_d - 64;
            const float bvc = bv[c];
            short* dst = vm + ((size_t)((b * 128 + blockIdx.x) * 512 + c)) * 32;
#pragma unroll
            for (int nt = 0; nt < 2; nt++) {
                union { long long ll; unsigned u2[2]; } pk;
                pk.u2[0] = cvt_pk_bf16(acc[nt][0] + bvc, acc[nt][1] + bvc);
                pk.u2[1] = cvt_pk_bf16(acc[nt][2] + bvc, acc[nt][3] + bvc);
                *(long long*)(dst + nt * 16 + 4 * l4) = pk.ll;
            }
        }
    }
}

// ---------------- Flash attention + residual (R9 champion, verbatim) ----------------
// 256 blocks x 8 waves, QBLK=64, j-macro=256, dbuf P 64 KB, pipelined CONSUME
// (V triple-buffered, P double-buffered), setprio, tiled V loads (1KB contig).
__global__ __launch_bounds__(512, 1) void attn_kernel(
    const short* __restrict__ qT, const short* __restrict__ kT,
    const short* __restrict__ vm, const float* __restrict__ x,
    const float* __restrict__ gamma, float* __restrict__ out)
{
    __shared__ short P_lds[2][32 * 512];   // [buf][frag = w*4+it][lane*8]
    __shared__ float red_lds[8][64];
    const int tid = threadIdx.x;
    const int lane = tid & 63;
    const int w = tid >> 6;
    const int l15 = lane & 15, l4 = lane >> 4;

    const int bid = blockIdx.x;
    const int xcd = bid & 7;
    const int idx = bid >> 3;            // 0..31
    const int b   = xcd >> 1;
    const int qt  = (xcd & 1) * 32 + idx;
    const int i0  = qt * 64;
    const int cb  = w * 64;

    short8 qf[4];
#pragma unroll
    for (int it = 0; it < 4; it++)
        qf[it] = *(const short8*)(qT + ((size_t)(b * 4096 + i0 + it * 16 + l15)) * 32 + 8 * l4);

    floatx4 acc[4][4];   // [ct][it]
#pragma unroll
    for (int ct = 0; ct < 4; ct++)
#pragma unroll
        for (int it = 0; it < 4; it++) acc[ct][it] = (floatx4)(0.0f);

    float l_[4] = {0.0f, 0.0f, 0.0f, 0.0f};

    const short* kb = kT + (size_t)b * 4096 * 32;
    const short* vb = vm + (size_t)b * 512 * 4096;   // tiled [jt][512][32]

#define PROD(T, KF0, KF1)                                                            \
    {                                                                                \
        const int buf = (T) & 1;                                                     \
        _Pragma("unroll")                                                            \
        for (int it = 0; it < 4; it++) {                                             \
            floatx4 s0 = mfma16((KF0), qf[it], (floatx4)(0.0f));                     \
            floatx4 s1 = mfma16((KF1), qf[it], (floatx4)(0.0f));                     \
            float p[8];                                                              \
            _Pragma("unroll")                                                        \
            for (int r = 0; r < 4; r++) {                                            \
                p[r]     = __builtin_amdgcn_exp2f(s0[r]);                            \
                p[4 + r] = __builtin_amdgcn_exp2f(s1[r]);                            \
            }                                                                        \
            union { short8 s; unsigned u[4]; } pk;                                   \
            _Pragma("unroll")                                                        \
            for (int j2 = 0; j2 < 4; j2++) pk.u[j2] = cvt_pk_bf16(p[2*j2], p[2*j2+1]); \
            *(short8*)&P_lds[buf][(w * 4 + it) * 512 + lane * 8] = pk.s;             \
            l_[it] += ((p[0] + p[1]) + (p[2] + p[3])) + ((p[4] + p[5]) + (p[6] + p[7])); \
        }                                                                            \
    }

#define VLOAD(T, JG, CT)                                                             \
    (*(const short8*)(vb + ((size_t)(((T) * 8 + (JG)) * 512 + cb + (CT) * 16 + l15)) * 32 + 8 * l4))
#define PREAD(BUF, JG, IT)                                                           \
    (*(const short8*)&P_lds[BUF][((JG) * 4 + (IT)) * 512 + lane * 8])

#define CONSUME(T)                                                                   \
    {                                                                                \
        const int buf = (T) & 1;                                                     \
        short8 vfp[3][4];                                                            \
        short8 pcp[2][4];                                                            \
        _Pragma("unroll")                                                            \
        for (int ct = 0; ct < 4; ct++) vfp[0][ct] = VLOAD(T, 0, ct);                 \
        _Pragma("unroll")                                                            \
        for (int ct = 0; ct < 4; ct++) vfp[1][ct] = VLOAD(T, 1, ct);                 \
        _Pragma("unroll")                                                            \
        for (int it = 0; it < 4; it++) pcp[0][it] = PREAD(buf, 0, it);               \
        _Pragma("unroll")                                                            \
        for (int jg = 0; jg < 8; jg++) {                                             \
            if (jg < 6) {                                                            \
                _Pragma("unroll")                                                    \
                for (int ct = 0; ct < 4; ct++)                                       \
                    vfp[(jg + 2) % 3][ct] = VLOAD(T, jg + 2, ct);                    \
            }                                                                        \
            if (jg < 7) {                                                            \
                _Pragma("unroll")                                                    \
                for (int it = 0; it < 4; it++)                                       \
                    pcp[(jg + 1) & 1][it] = PREAD(buf, jg + 1, it);                  \
            }                                                                        \
            __builtin_amdgcn_s_setprio(1);                                           \
            _Pragma("unroll")                                                        \
            for (int ct = 0; ct < 4; ct++)                                           \
                _Pragma("unroll")                                                    \
                for (int it = 0; it < 4; it++)                                       \
                    acc[ct][it] = mfma16(vfp[jg % 3][ct], pcp[jg & 1][it], acc[ct][it]); \
            __builtin_amdgcn_s_setprio(0);                                           \
        }                                                                            \
    }

    // prologue: produce macro-tile 0
    {
        short8 kf0 = *(const short8*)(kb + (size_t)(w * 32 + l15) * 32 + 8 * l4);
        short8 kf1 = *(const short8*)(kb + (size_t)(w * 32 + 16 + l15) * 32 + 8 * l4);
        PROD(0, kf0, kf1);
    }

#pragma unroll 1
    for (int t = 0; t < 16; t++) {
        __syncthreads();
        short8 nk0, nk1;
        if (t < 15) {   // hoist next K loads; latency hides under CONSUME
            const int jj = (t + 1) * 256 + w * 32;
            nk0 = *(const short8*)(kb + (size_t)(jj + l15) * 32 + 8 * l4);
            nk1 = *(const short8*)(kb + (size_t)(jj + 16 + l15) * 32 + 8 * l4);
        }
        CONSUME(t);
        if (t < 15) PROD(t + 1, nk0, nk1);
    }
#undef PROD
#undef CONSUME
#undef VLOAD
#undef PREAD

    // l: reduce within wave, then across 8 waves via LDS
#pragma unroll
    for (int it = 0; it < 4; it++) {
        l_[it] += __shfl_xor(l_[it], 16, 64);
        l_[it] += __shfl_xor(l_[it], 32, 64);
    }
    if (lane < 16)
#pragma unroll
        for (int it = 0; it < 4; it++) red_lds[w][it * 16 + lane] = l_[it];
    __syncthreads();

    const float g = gamma[0];
    float inv[4];
#pragma unroll
    for (int it = 0; it < 4; it++) {
        float s = 0.0f;
#pragma unroll
        for (int ww = 0; ww < 8; ww++) s += red_lds[ww][it * 16 + l15];
        inv[it] = g / s;
    }

#pragma unroll
    for (int ct = 0; ct < 4; ct++)
#pragma unroll
        for (int it = 0; it < 4; it++)
#pragma unroll
            for (int r = 0; r < 4; r++) {
                const int c = cb + ct * 16 + 4 * l4 + r;
                const int i = i0 + it * 16 + l15;
                const size_t o = ((size_t)(b * 512 + c)) * 4096 + i;
                out[o] = acc[ct][it][r] * inv[it] + x[o];
            }
}

extern "C" void kernel_launch(void* const* d_in, const int* in_sizes, int n_in,
                              void* d_out, int out_size, void* d_ws, size_t ws_size,
                              hipStream_t stream) {
    const float* x     = (const float*)d_in[0];
    const float* wq    = (const float*)d_in[1];
    const float* bq    = (const float*)d_in[2];
    const float* wk    = (const float*)d_in[3];
    const float* bk    = (const float*)d_in[4];
    const float* wv    = (const float*)d_in[5];
    const float* bv    = (const float*)d_in[6];
    const float* gamma = (const float*)d_in[7];
    float* out = (float*)d_out;

    short* qT = (short*)d_ws;                  // 1 MB
    short* kT = qT + (size_t)4 * 4096 * 32;    // 1 MB
    short* vm = kT + (size_t)4 * 4096 * 32;    // 16 MB (tiled [b][jt][512][32])
    short* wb = vm + (size_t)4 * 512 * 4096;   // 0.56 MB (tiled)

    wcvt_kernel<<<288, 256, 0, stream>>>(wq, wk, wv, wb);
    proj_kernel<<<dim3(128, 2, 4), 256, 0, stream>>>(x, wb, bq, bk, bv, qT, kT, vm);
    attn_kernel<<<256, 512, 0, stream>>>(qT, kT, vm, x, gamma, out);
}

// Round 17
// 117.033 us; speedup vs baseline: 1.3889x; 1.0411x over previous
//
#include <hip/hip_runtime.h>
#include <hip/hip_bf16.h>

#define LOG2E 1.44269504088896340736f

typedef __attribute__((ext_vector_type(8))) short short8;
typedef __attribute__((ext_vector_type(4))) float floatx4;

static __device__ __forceinline__ short f2bf(float f) {
    union { float f; unsigned u; } v; v.f = f;
    unsigned r = (v.u + 0x7FFF + ((v.u >> 16) & 1)) >> 16;  // RNE
    return (short)r;
}

static __device__ __forceinline__ floatx4 mfma16(short8 a, short8 b, floatx4 c) {
    return __builtin_amdgcn_mfma_f32_16x16x32_bf16(a, b, c, 0, 0, 0);
}

static __device__ __forceinline__ unsigned cvt_pk_bf16(float lo, float hi) {
    unsigned u;
    asm("v_cvt_pk_bf16_f32 %0, %1, %2" : "=v"(u) : "v"(lo), "v"(hi));
    return u;
}

// ---------------- Weight pre-convert: wb tiled [(ot*16+cg)][64 o][32 c] ----------------
__global__ __launch_bounds__(256) void wcvt_kernel(
    const float* __restrict__ wq, const float* __restrict__ wk,
    const float* __restrict__ wv, short* __restrict__ wb)
{
    const int idx = (blockIdx.x * 256 + threadIdx.x) * 4;   // 294912 total
    const int row = idx >> 9;          // 0..575
    const int col = idx & 511;
    const float* src;
    float sc = 1.0f;
    if (row < 32)      { src = wq + (size_t)row * 512; sc = LOG2E; }
    else if (row < 64) { src = wk + (size_t)(row - 32) * 512; }
    else               { src = wv + (size_t)(row - 64) * 512; }
    floatx4 v = *(const floatx4*)(src + col);
    union { short s[4]; long long ll; } o;
#pragma unroll
    for (int u = 0; u < 4; u++) o.s[u] = f2bf(v[u] * sc);
    const int didx = (((row >> 6) * 16 + (col >> 5)) * 64 + (row & 63)) * 32 + (col & 31);
    *(long long*)(wb + didx) = o.ll;
}

// ---------------- Projection (R15 version, measured best) ----------------
// grid (128 n-tiles of 32, 2 o-groups, B), block 256 (4 waves), 4 blocks/CU.
__global__ __launch_bounds__(256) void proj_kernel(
    const float* __restrict__ x, const short* __restrict__ wb,
    const float* __restrict__ bq, const float* __restrict__ bk,
    const float* __restrict__ bv,
    short* __restrict__ qT, short* __restrict__ kT, short* __restrict__ vm)
{
    __shared__ short xT[32 * 520];   // [n][c] bf16, pitch 520
    const int tid = threadIdx.x;
    const int w = tid >> 6;
    const int lane = tid & 63;
    const int l15 = lane & 15, l4 = lane >> 4;
    const int n0 = blockIdx.x * 32;
    const int og = blockIdx.y;       // 0: ot 0..4, 1: ot 5..8
    const int b  = blockIdx.z;

    const float* xb = x + (size_t)b * 512 * 4096;

    const int cp = tid >> 3;          // 0..31
    const int nq = (tid & 7) * 4;     // 0,4,..,28
#pragma unroll
    for (int p = 0; p < 8; p++) {
        const int c = (p * 32 + cp) * 2;
        const float* r0 = xb + (size_t)c * 4096 + n0 + nq;
        const float* r1 = r0 + 4096;
        floatx4 xa = *(const floatx4*)r0;
        floatx4 xc = *(const floatx4*)r1;
#pragma unroll
        for (int u = 0; u < 4; u++)
            *(unsigned*)&xT[(nq + u) * 520 + c] = cvt_pk_bf16(xa[u], xc[u]);
    }
    __syncthreads();

    const int ot_start = og * 5;          // 0 or 5
    const int ot_count = 5 - og;          // 5 or 4
#pragma unroll 1
    for (int oi = 0; oi < ot_count; oi++) {
        const int ot = ot_start + oi;
        floatx4 acc[2];
#pragma unroll
        for (int i = 0; i < 2; i++) acc[i] = (floatx4)(0.0f);

#pragma unroll 4
        for (int c0 = 0; c0 < 512; c0 += 32) {
            short8 wf = *(const short8*)(wb + ((size_t)(ot * 16 + (c0 >> 5)) * 64
                                               + w * 16 + l15) * 32 + 8 * l4);
#pragma unroll
            for (int nt = 0; nt < 2; nt++) {
                short8 xf = *(const short8*)&xT[(nt * 16 + l15) * 520 + c0 + 8 * l4];
                acc[nt] = mfma16(xf, wf, acc[nt]);   // swapped: D[l15->o][4l4+r->n]
            }
        }

        const int o_d = ot * 64 + w * 16 + l15;
        if (o_d < 32) {
            const float bqe = bq[o_d] * LOG2E;
#pragma unroll
            for (int nt = 0; nt < 2; nt++)
#pragma unroll
                for (int r = 0; r < 4; r++) {
                    const int n = n0 + nt * 16 + 4 * l4 + r;
                    qT[((size_t)(b * 4096 + n)) * 32 + o_d] = f2bf(acc[nt][r] + bqe);
                }
        } else if (o_d < 64) {
            const float bke = bk[o_d - 32];
#pragma unroll
            for (int nt = 0; nt < 2; nt++)
#pragma unroll
                for (int r = 0; r < 4; r++) {
                    const int n = n0 + nt * 16 + 4 * l4 + r;
                    const int s = n & 31;
                    const int p2 = 16 * ((s >> 2) & 1) + 4 * (s >> 3) + (s & 3);
                    const int nst = (n & ~31) | p2;
                    kT[((size_t)(b * 4096 + nst)) * 32 + (o_d - 32)] = f2bf(acc[nt][r] + bke);
                }
        } else {
            const int c = o_d - 64;
            const float bvc = bv[c];
            short* dst = vm + ((size_t)((b * 128 + blockIdx.x) * 512 + c)) * 32;
#pragma unroll
            for (int nt = 0; nt < 2; nt++) {
                union { long long ll; unsigned u2[2]; } pk;
                pk.u2[0] = cvt_pk_bf16(acc[nt][0] + bvc, acc[nt][1] + bvc);
                pk.u2[1] = cvt_pk_bf16(acc[nt][2] + bvc, acc[nt][3] + bvc);
                *(long long*)(dst + nt * 16 + 4 * l4) = pk.ll;
            }
        }
    }
}

// ---------------- Flash attention + residual ----------------
// R9 structure + STAGGERED WAVE PHASES: waves 0-3 do CONSUME(t);PROD(t+1),
// waves 4-7 do PROD(t+1);CONSUME(t). Waves round-robin onto SIMDs, so each
// SIMD pairs an MFMA-heavy wave with a trans/VALU-heavy wave -> heterogeneous
// pipe overlap (m114), and setprio gets a real role-split (T5 regime).
// Correctness: within a barrier region consume reads buf[t&1], prod writes
// buf[(t+1)&1]; WAR vs prev consume of that buffer is guarded by the top
// barrier. Pure reorder, no sync change.
__global__ __launch_bounds__(512, 1) void attn_kernel(
    const short* __restrict__ qT, const short* __restrict__ kT,
    const short* __restrict__ vm, const float* __restrict__ x,
    const float* __restrict__ gamma, float* __restrict__ out)
{
    __shared__ short P_lds[2][32 * 512];   // [buf][frag = w*4+it][lane*8]
    __shared__ float red_lds[8][64];
    const int tid = threadIdx.x;
    const int lane = tid & 63;
    const int w = tid >> 6;
    const int l15 = lane & 15, l4 = lane >> 4;

    const int bid = blockIdx.x;
    const int xcd = bid & 7;
    const int idx = bid >> 3;            // 0..31
    const int b   = xcd >> 1;
    const int qt  = (xcd & 1) * 32 + idx;
    const int i0  = qt * 64;
    const int cb  = w * 64;

    short8 qf[4];
#pragma unroll
    for (int it = 0; it < 4; it++)
        qf[it] = *(const short8*)(qT + ((size_t)(b * 4096 + i0 + it * 16 + l15)) * 32 + 8 * l4);

    floatx4 acc[4][4];   // [ct][it]
#pragma unroll
    for (int ct = 0; ct < 4; ct++)
#pragma unroll
        for (int it = 0; it < 4; it++) acc[ct][it] = (floatx4)(0.0f);

    float l_[4] = {0.0f, 0.0f, 0.0f, 0.0f};

    const short* kb = kT + (size_t)b * 4096 * 32;
    const short* vb = vm + (size_t)b * 512 * 4096;   // tiled [jt][512][32]

#define PROD(T, KF0, KF1)                                                            \
    {                                                                                \
        const int buf = (T) & 1;                                                     \
        _Pragma("unroll")                                                            \
        for (int it = 0; it < 4; it++) {                                             \
            floatx4 s0 = mfma16((KF0), qf[it], (floatx4)(0.0f));                     \
            floatx4 s1 = mfma16((KF1), qf[it], (floatx4)(0.0f));                     \
            float p[8];                                                              \
            _Pragma("unroll")                                                        \
            for (int r = 0; r < 4; r++) {                                            \
                p[r]     = __builtin_amdgcn_exp2f(s0[r]);                            \
                p[4 + r] = __builtin_amdgcn_exp2f(s1[r]);                            \
            }                                                                        \
            union { short8 s; unsigned u[4]; } pk;                                   \
            _Pragma("unroll")                                                        \
            for (int j2 = 0; j2 < 4; j2++) pk.u[j2] = cvt_pk_bf16(p[2*j2], p[2*j2+1]); \
            *(short8*)&P_lds[buf][(w * 4 + it) * 512 + lane * 8] = pk.s;             \
            l_[it] += ((p[0] + p[1]) + (p[2] + p[3])) + ((p[4] + p[5]) + (p[6] + p[7])); \
        }                                                                            \
    }

#define VLOAD(T, JG, CT)                                                             \
    (*(const short8*)(vb + ((size_t)(((T) * 8 + (JG)) * 512 + cb + (CT) * 16 + l15)) * 32 + 8 * l4))
#define PREAD(BUF, JG, IT)                                                           \
    (*(const short8*)&P_lds[BUF][((JG) * 4 + (IT)) * 512 + lane * 8])

#define CONSUME(T)                                                                   \
    {                                                                                \
        const int buf = (T) & 1;                                                     \
        short8 vfp[3][4];                                                            \
        short8 pcp[2][4];                                                            \
        _Pragma("unroll")                                                            \
        for (int ct = 0; ct < 4; ct++) vfp[0][ct] = VLOAD(T, 0, ct);                 \
        _Pragma("unroll")                                                            \
        for (int ct = 0; ct < 4; ct++) vfp[1][ct] = VLOAD(T, 1, ct);                 \
        _Pragma("unroll")                                                            \
        for (int it = 0; it < 4; it++) pcp[0][it] = PREAD(buf, 0, it);               \
        _Pragma("unroll")                                                            \
        for (int jg = 0; jg < 8; jg++) {                                             \
            if (jg < 6) {                                                            \
                _Pragma("unroll")                                                    \
                for (int ct = 0; ct < 4; ct++)                                       \
                    vfp[(jg + 2) % 3][ct] = VLOAD(T, jg + 2, ct);                    \
            }                                                                        \
            if (jg < 7) {                                                            \
                _Pragma("unroll")                                                    \
                for (int it = 0; it < 4; it++)                                       \
                    pcp[(jg + 1) & 1][it] = PREAD(buf, jg + 1, it);                  \
            }                                                                        \
            __builtin_amdgcn_s_setprio(1);                                           \
            _Pragma("unroll")                                                        \
            for (int ct = 0; ct < 4; ct++)                                           \
                _Pragma("unroll")                                                    \
                for (int it = 0; it < 4; it++)                                       \
                    acc[ct][it] = mfma16(vfp[jg % 3][ct], pcp[jg & 1][it], acc[ct][it]); \
            __builtin_amdgcn_s_setprio(0);                                           \
        }                                                                            \
    }

    // prologue: produce macro-tile 0
    {
        short8 kf0 = *(const short8*)(kb + (size_t)(w * 32 + l15) * 32 + 8 * l4);
        short8 kf1 = *(const short8*)(kb + (size_t)(w * 32 + 16 + l15) * 32 + 8 * l4);
        PROD(0, kf0, kf1);
    }

    const bool early = (w < 4);   // wave-uniform phase split

#pragma unroll 1
    for (int t = 0; t < 16; t++) {
        __syncthreads();
        short8 nk0, nk1;
        if (t < 15) {
            const int jj = (t + 1) * 256 + w * 32;
            nk0 = *(const short8*)(kb + (size_t)(jj + l15) * 32 + 8 * l4);
            nk1 = *(const short8*)(kb + (size_t)(jj + 16 + l15) * 32 + 8 * l4);
        }
        if (early) {
            CONSUME(t);
            if (t < 15) PROD(t + 1, nk0, nk1);
        } else {
            if (t < 15) PROD(t + 1, nk0, nk1);
            CONSUME(t);
        }
    }
#undef PROD
#undef CONSUME
#undef VLOAD
#undef PREAD

    // l: reduce within wave, then across 8 waves via LDS
#pragma unroll
    for (int it = 0; it < 4; it++) {
        l_[it] += __shfl_xor(l_[it], 16, 64);
        l_[it] += __shfl_xor(l_[it], 32, 64);
    }
    if (lane < 16)
#pragma unroll
        for (int it = 0; it < 4; it++) red_lds[w][it * 16 + lane] = l_[it];
    __syncthreads();

    const float g = gamma[0];
    float inv[4];
#pragma unroll
    for (int it = 0; it < 4; it++) {
        float s = 0.0f;
#pragma unroll
        for (int ww = 0; ww < 8; ww++) s += red_lds[ww][it * 16 + l15];
        inv[it] = g / s;
    }

#pragma unroll
    for (int ct = 0; ct < 4; ct++)
#pragma unroll
        for (int it = 0; it < 4; it++)
#pragma unroll
            for (int r = 0; r < 4; r++) {
                const int c = cb + ct * 16 + 4 * l4 + r;
                const int i = i0 + it * 16 + l15;
                const size_t o = ((size_t)(b * 512 + c)) * 4096 + i;
                out[o] = acc[ct][it][r] * inv[it] + x[o];
            }
}

extern "C" void kernel_launch(void* const* d_in, const int* in_sizes, int n_in,
                              void* d_out, int out_size, void* d_ws, size_t ws_size,
                              hipStream_t stream) {
    const float* x     = (const float*)d_in[0];
    const float* wq    = (const float*)d_in[1];
    const float* bq    = (const float*)d_in[2];
    const float* wk    = (const float*)d_in[3];
    const float* bk    = (const float*)d_in[4];
    const float* wv    = (const float*)d_in[5];
    const float* bv    = (const float*)d_in[6];
    const float* gamma = (const float*)d_in[7];
    float* out = (float*)d_out;

    short* qT = (short*)d_ws;                  // 1 MB
    short* kT = qT + (size_t)4 * 4096 * 32;    // 1 MB
    short* vm = kT + (size_t)4 * 4096 * 32;    // 16 MB (tiled [b][jt][512][32])
    short* wb = vm + (size_t)4 * 512 * 4096;   // 0.56 MB (tiled)

    wcvt_kernel<<<288, 256, 0, stream>>>(wq, wk, wv, wb);
    proj_kernel<<<dim3(128, 2, 4), 256, 0, stream>>>(x, wb, bq, bk, bv, qT, kT, vm);
    attn_kernel<<<256, 512, 0, stream>>>(qT, kT, vm, x, gamma, out);
}

// Round 18
// 116.344 us; speedup vs baseline: 1.3972x; 1.0059x over previous
//
#include <hip/hip_runtime.h>
#include <hip/hip_bf16.h>

#define LOG2E 1.44269504088896340736f

typedef __attribute__((ext_vector_type(8))) short short8;
typedef __attribute__((ext_vector_type(4))) float floatx4;

static __device__ __forceinline__ short f2bf(float f) {
    union { float f; unsigned u; } v; v.f = f;
    unsigned r = (v.u + 0x7FFF + ((v.u >> 16) & 1)) >> 16;  // RNE
    return (short)r;
}

static __device__ __forceinline__ float bf2f(short s) {
    union { float f; unsigned u; } v; v.u = ((unsigned)(unsigned short)s) << 16;
    return v.f;
}

static __device__ __forceinline__ floatx4 mfma16(short8 a, short8 b, floatx4 c) {
    return __builtin_amdgcn_mfma_f32_16x16x32_bf16(a, b, c, 0, 0, 0);
}

static __device__ __forceinline__ unsigned cvt_pk_bf16(float lo, float hi) {
    unsigned u;
    asm("v_cvt_pk_bf16_f32 %0, %1, %2" : "=v"(u) : "v"(lo), "v"(hi));
    return u;
}

// ---------------- Weight pre-convert: wb tiled [(ot*16+cg)][64 o][32 c] ----------------
__global__ __launch_bounds__(256) void wcvt_kernel(
    const float* __restrict__ wq, const float* __restrict__ wk,
    const float* __restrict__ wv, short* __restrict__ wb)
{
    const int idx = (blockIdx.x * 256 + threadIdx.x) * 4;   // 294912 total
    const int row = idx >> 9;          // 0..575
    const int col = idx & 511;
    const float* src;
    float sc = 1.0f;
    if (row < 32)      { src = wq + (size_t)row * 512; sc = LOG2E; }
    else if (row < 64) { src = wk + (size_t)(row - 32) * 512; }
    else               { src = wv + (size_t)(row - 64) * 512; }
    floatx4 v = *(const floatx4*)(src + col);
    union { short s[4]; long long ll; } o;
#pragma unroll
    for (int u = 0; u < 4; u++) o.s[u] = f2bf(v[u] * sc);
    const int didx = (((row >> 6) * 16 + (col >> 5)) * 64 + (row & 63)) * 32 + (col & 31);
    *(long long*)(wb + didx) = o.ll;
}

// ---------------- Projection (R15 version, measured best) ----------------
__global__ __launch_bounds__(256) void proj_kernel(
    const float* __restrict__ x, const short* __restrict__ wb,
    const float* __restrict__ bq, const float* __restrict__ bk,
    const float* __restrict__ bv,
    short* __restrict__ qT, short* __restrict__ kT, short* __restrict__ vm)
{
    __shared__ short xT[32 * 520];   // [n][c] bf16, pitch 520
    const int tid = threadIdx.x;
    const int w = tid >> 6;
    const int lane = tid & 63;
    const int l15 = lane & 15, l4 = lane >> 4;
    const int n0 = blockIdx.x * 32;
    const int og = blockIdx.y;       // 0: ot 0..4, 1: ot 5..8
    const int b  = blockIdx.z;

    const float* xb = x + (size_t)b * 512 * 4096;

    const int cp = tid >> 3;          // 0..31
    const int nq = (tid & 7) * 4;     // 0,4,..,28
#pragma unroll
    for (int p = 0; p < 8; p++) {
        const int c = (p * 32 + cp) * 2;
        const float* r0 = xb + (size_t)c * 4096 + n0 + nq;
        const float* r1 = r0 + 4096;
        floatx4 xa = *(const floatx4*)r0;
        floatx4 xc = *(const floatx4*)r1;
#pragma unroll
        for (int u = 0; u < 4; u++)
            *(unsigned*)&xT[(nq + u) * 520 + c] = cvt_pk_bf16(xa[u], xc[u]);
    }
    __syncthreads();

    const int ot_start = og * 5;          // 0 or 5
    const int ot_count = 5 - og;          // 5 or 4
#pragma unroll 1
    for (int oi = 0; oi < ot_count; oi++) {
        const int ot = ot_start + oi;
        floatx4 acc[2];
#pragma unroll
        for (int i = 0; i < 2; i++) acc[i] = (floatx4)(0.0f);

#pragma unroll 4
        for (int c0 = 0; c0 < 512; c0 += 32) {
            short8 wf = *(const short8*)(wb + ((size_t)(ot * 16 + (c0 >> 5)) * 64
                                               + w * 16 + l15) * 32 + 8 * l4);
#pragma unroll
            for (int nt = 0; nt < 2; nt++) {
                short8 xf = *(const short8*)&xT[(nt * 16 + l15) * 520 + c0 + 8 * l4];
                acc[nt] = mfma16(xf, wf, acc[nt]);   // swapped: D[l15->o][4l4+r->n]
            }
        }

        const int o_d = ot * 64 + w * 16 + l15;
        if (o_d < 32) {
            const float bqe = bq[o_d] * LOG2E;
#pragma unroll
            for (int nt = 0; nt < 2; nt++)
#pragma unroll
                for (int r = 0; r < 4; r++) {
                    const int n = n0 + nt * 16 + 4 * l4 + r;
                    qT[((size_t)(b * 4096 + n)) * 32 + o_d] = f2bf(acc[nt][r] + bqe);
                }
        } else if (o_d < 64) {
            const float bke = bk[o_d - 32];
#pragma unroll
            for (int nt = 0; nt < 2; nt++)
#pragma unroll
                for (int r = 0; r < 4; r++) {
                    const int n = n0 + nt * 16 + 4 * l4 + r;
                    const int s = n & 31;
                    const int p2 = 16 * ((s >> 2) & 1) + 4 * (s >> 3) + (s & 3);
                    const int nst = (n & ~31) | p2;
                    kT[((size_t)(b * 4096 + nst)) * 32 + (o_d - 32)] = f2bf(acc[nt][r] + bke);
                }
        } else {
            const int c = o_d - 64;
            const float bvc = bv[c];
            short* dst = vm + ((size_t)((b * 128 + blockIdx.x) * 512 + c)) * 32;
#pragma unroll
            for (int nt = 0; nt < 2; nt++) {
                union { long long ll; unsigned u2[2]; } pk;
                pk.u2[0] = cvt_pk_bf16(acc[nt][0] + bvc, acc[nt][1] + bvc);
                pk.u2[1] = cvt_pk_bf16(acc[nt][2] + bvc, acc[nt][3] + bvc);
                *(long long*)(dst + nt * 16 + 4 * l4) = pk.ll;
            }
        }
    }
}

// ---------------- Flash attention + residual ----------------
// R16 structure (staggered wave phases) + x-residual prefetched into LDS at
// t==13: each wave stages its own 64 c-rows (16x dwordx4, 1KB contig/instr,
// cvt_pk -> b64) so the epilogue's 34 MB x-read overlaps the loop instead of
// being a serialized tail burst. Epilogue reads x from LDS (bf16, +<=0.005 err).
__global__ __launch_bounds__(512, 1) void attn_kernel(
    const short* __restrict__ qT, const short* __restrict__ kT,
    const short* __restrict__ vm, const float* __restrict__ x,
    const float* __restrict__ gamma, float* __restrict__ out)
{
    __shared__ short P_lds[2][32 * 512];   // [buf][frag = w*4+it][lane*8]  64 KB
    __shared__ float red_lds[8][64];       // 2 KB
    __shared__ short x_lds[512 * 68];      // [c][i_local], pitch 68 -> 69.6 KB
    const int tid = threadIdx.x;
    const int lane = tid & 63;
    const int w = tid >> 6;
    const int l15 = lane & 15, l4 = lane >> 4;

    const int bid = blockIdx.x;
    const int xcd = bid & 7;
    const int idx = bid >> 3;            // 0..31
    const int b   = xcd >> 1;
    const int qt  = (xcd & 1) * 32 + idx;
    const int i0  = qt * 64;
    const int cb  = w * 64;

    short8 qf[4];
#pragma unroll
    for (int it = 0; it < 4; it++)
        qf[it] = *(const short8*)(qT + ((size_t)(b * 4096 + i0 + it * 16 + l15)) * 32 + 8 * l4);

    floatx4 acc[4][4];   // [ct][it]
#pragma unroll
    for (int ct = 0; ct < 4; ct++)
#pragma unroll
        for (int it = 0; it < 4; it++) acc[ct][it] = (floatx4)(0.0f);

    float l_[4] = {0.0f, 0.0f, 0.0f, 0.0f};

    const short* kb = kT + (size_t)b * 4096 * 32;
    const short* vb = vm + (size_t)b * 512 * 4096;   // tiled [jt][512][32]
    const float* xb = x + (size_t)b * 512 * 4096;

#define PROD(T, KF0, KF1)                                                            \
    {                                                                                \
        const int buf = (T) & 1;                                                     \
        _Pragma("unroll")                                                            \
        for (int it = 0; it < 4; it++) {                                             \
            floatx4 s0 = mfma16((KF0), qf[it], (floatx4)(0.0f));                     \
            floatx4 s1 = mfma16((KF1), qf[it], (floatx4)(0.0f));                     \
            float p[8];                                                              \
            _Pragma("unroll")                                                        \
            for (int r = 0; r < 4; r++) {                                            \
                p[r]     = __builtin_amdgcn_exp2f(s0[r]);                            \
                p[4 + r] = __builtin_amdgcn_exp2f(s1[r]);                            \
            }                                                                        \
            union { short8 s; unsigned u[4]; } pk;                                   \
            _Pragma("unroll")                                                        \
            for (int j2 = 0; j2 < 4; j2++) pk.u[j2] = cvt_pk_bf16(p[2*j2], p[2*j2+1]); \
            *(short8*)&P_lds[buf][(w * 4 + it) * 512 + lane * 8] = pk.s;             \
            l_[it] += ((p[0] + p[1]) + (p[2] + p[3])) + ((p[4] + p[5]) + (p[6] + p[7])); \
        }                                                                            \
    }

#define VLOAD(T, JG, CT)                                                             \
    (*(const short8*)(vb + ((size_t)(((T) * 8 + (JG)) * 512 + cb + (CT) * 16 + l15)) * 32 + 8 * l4))
#define PREAD(BUF, JG, IT)                                                           \
    (*(const short8*)&P_lds[BUF][((JG) * 4 + (IT)) * 512 + lane * 8])

#define CONSUME(T)                                                                   \
    {                                                                                \
        const int buf = (T) & 1;                                                     \
        short8 vfp[3][4];                                                            \
        short8 pcp[2][4];                                                            \
        _Pragma("unroll")                                                            \
        for (int ct = 0; ct < 4; ct++) vfp[0][ct] = VLOAD(T, 0, ct);                 \
        _Pragma("unroll")                                                            \
        for (int ct = 0; ct < 4; ct++) vfp[1][ct] = VLOAD(T, 1, ct);                 \
        _Pragma("unroll")                                                            \
        for (int it = 0; it < 4; it++) pcp[0][it] = PREAD(buf, 0, it);               \
        _Pragma("unroll")                                                            \
        for (int jg = 0; jg < 8; jg++) {                                             \
            if (jg < 6) {                                                            \
                _Pragma("unroll")                                                    \
                for (int ct = 0; ct < 4; ct++)                                       \
                    vfp[(jg + 2) % 3][ct] = VLOAD(T, jg + 2, ct);                    \
            }                                                                        \
            if (jg < 7) {                                                            \
                _Pragma("unroll")                                                    \
                for (int it = 0; it < 4; it++)                                       \
                    pcp[(jg + 1) & 1][it] = PREAD(buf, jg + 1, it);                  \
            }                                                                        \
            __builtin_amdgcn_s_setprio(1);                                           \
            _Pragma("unroll")                                                        \
            for (int ct = 0; ct < 4; ct++)                                           \
                _Pragma("unroll")                                                    \
                for (int it = 0; it < 4; it++)                                       \
                    acc[ct][it] = mfma16(vfp[jg % 3][ct], pcp[jg & 1][it], acc[ct][it]); \
            __builtin_amdgcn_s_setprio(0);                                           \
        }                                                                            \
    }

    // prologue: produce macro-tile 0
    {
        short8 kf0 = *(const short8*)(kb + (size_t)(w * 32 + l15) * 32 + 8 * l4);
        short8 kf1 = *(const short8*)(kb + (size_t)(w * 32 + 16 + l15) * 32 + 8 * l4);
        PROD(0, kf0, kf1);
    }

    const bool early = (w < 4);   // wave-uniform phase split

#pragma unroll 1
    for (int t = 0; t < 16; t++) {
        __syncthreads();
        short8 nk0, nk1;
        if (t < 15) {
            const int jj = (t + 1) * 256 + w * 32;
            nk0 = *(const short8*)(kb + (size_t)(jj + l15) * 32 + 8 * l4);
            nk1 = *(const short8*)(kb + (size_t)(jj + 16 + l15) * 32 + 8 * l4);
        }
        if (early) {
            CONSUME(t);
            if (t < 15) PROD(t + 1, nk0, nk1);
        } else {
            if (t < 15) PROD(t + 1, nk0, nk1);
            CONSUME(t);
        }
        if (t == 13) {
            // stage this wave's 64 x-rows into LDS: 16x (dwordx4 = 4 contig
            // 256B rows/instr) + cvt_pk + ds_write_b64. Visible to epilogue
            // via the post-loop __syncthreads().
#pragma unroll
            for (int u = 0; u < 16; u++) {
                const int row = w * 64 + u * 4 + l4;
                floatx4 xv = *(const floatx4*)(xb + (size_t)row * 4096 + i0 + l15 * 4);
                union { long long ll; unsigned u2[2]; } pk;
                pk.u2[0] = cvt_pk_bf16(xv[0], xv[1]);
                pk.u2[1] = cvt_pk_bf16(xv[2], xv[3]);
                *(long long*)&x_lds[row * 68 + l15 * 4] = pk.ll;
            }
        }
    }
#undef PROD
#undef CONSUME
#undef VLOAD
#undef PREAD

    // l: reduce within wave, then across 8 waves via LDS
#pragma unroll
    for (int it = 0; it < 4; it++) {
        l_[it] += __shfl_xor(l_[it], 16, 64);
        l_[it] += __shfl_xor(l_[it], 32, 64);
    }
    if (lane < 16)
#pragma unroll
        for (int it = 0; it < 4; it++) red_lds[w][it * 16 + lane] = l_[it];
    __syncthreads();

    const float g = gamma[0];
    float inv[4];
#pragma unroll
    for (int it = 0; it < 4; it++) {
        float s = 0.0f;
#pragma unroll
        for (int ww = 0; ww < 8; ww++) s += red_lds[ww][it * 16 + l15];
        inv[it] = g / s;
    }

#pragma unroll
    for (int ct = 0; ct < 4; ct++)
#pragma unroll
        for (int it = 0; it < 4; it++)
#pragma unroll
            for (int r = 0; r < 4; r++) {
                const int c = cb + ct * 16 + 4 * l4 + r;
                const int i = i0 + it * 16 + l15;
                const size_t o = ((size_t)(b * 512 + c)) * 4096 + i;
                out[o] = acc[ct][it][r] * inv[it] + bf2f(x_lds[c * 68 + it * 16 + l15]);
            }
}

extern "C" void kernel_launch(void* const* d_in, const int* in_sizes, int n_in,
                              void* d_out, int out_size, void* d_ws, size_t ws_size,
                              hipStream_t stream) {
    const float* x     = (const float*)d_in[0];
    const float* wq    = (const float*)d_in[1];
    const float* bq    = (const float*)d_in[2];
    const float* wk    = (const float*)d_in[3];
    const float* bk    = (const float*)d_in[4];
    const float* wv    = (const float*)d_in[5];
    const float* bv    = (const float*)d_in[6];
    const float* gamma = (const float*)d_in[7];
    float* out = (float*)d_out;

    short* qT = (short*)d_ws;                  // 1 MB
    short* kT = qT + (size_t)4 * 4096 * 32;    // 1 MB
    short* vm = kT + (size_t)4 * 4096 * 32;    // 16 MB (tiled [b][jt][512][32])
    short* wb = vm + (size_t)4 * 512 * 4096;   // 0.56 MB (tiled)

    wcvt_kernel<<<288, 256, 0, stream>>>(wq, wk, wv, wb);
    proj_kernel<<<dim3(128, 2, 4), 256, 0, stream>>>(x, wb, bq, bk, bv, qT, kT, vm);
    attn_kernel<<<256, 512, 0, stream>>>(qT, kT, vm, x, gamma, out);
}

// Round 19
// 116.042 us; speedup vs baseline: 1.4008x; 1.0026x over previous
//
#include <hip/hip_runtime.h>
#include <hip/hip_bf16.h>

#define LOG2E 1.44269504088896340736f

typedef __attribute__((ext_vector_type(8))) short short8;
typedef __attribute__((ext_vector_type(4))) float floatx4;

static __device__ __forceinline__ short f2bf(float f) {
    union { float f; unsigned u; } v; v.f = f;
    unsigned r = (v.u + 0x7FFF + ((v.u >> 16) & 1)) >> 16;  // RNE
    return (short)r;
}

static __device__ __forceinline__ float bf2f(short s) {
    union { float f; unsigned u; } v; v.u = ((unsigned)(unsigned short)s) << 16;
    return v.f;
}

static __device__ __forceinline__ floatx4 mfma16(short8 a, short8 b, floatx4 c) {
    return __builtin_amdgcn_mfma_f32_16x16x32_bf16(a, b, c, 0, 0, 0);
}

static __device__ __forceinline__ unsigned cvt_pk_bf16(float lo, float hi) {
    unsigned u;
    asm("v_cvt_pk_bf16_f32 %0, %1, %2" : "=v"(u) : "v"(lo), "v"(hi));
    return u;
}

// LDS-only barrier: waits LDS ops (P/x visibility) but does NOT drain vmcnt,
// so V/K global prefetches survive across tile boundaries (T4 essence).
// Safe here: cross-wave communication in the loop is exclusively via LDS.
static __device__ __forceinline__ void lds_barrier() {
    asm volatile("s_waitcnt lgkmcnt(0)" ::: "memory");
    __builtin_amdgcn_s_barrier();
}

// ---------------- Weight pre-convert: wb tiled [(ot*16+cg)][64 o][32 c] ----------------
__global__ __launch_bounds__(256) void wcvt_kernel(
    const float* __restrict__ wq, const float* __restrict__ wk,
    const float* __restrict__ wv, short* __restrict__ wb)
{
    const int idx = (blockIdx.x * 256 + threadIdx.x) * 4;   // 294912 total
    const int row = idx >> 9;          // 0..575
    const int col = idx & 511;
    const float* src;
    float sc = 1.0f;
    if (row < 32)      { src = wq + (size_t)row * 512; sc = LOG2E; }
    else if (row < 64) { src = wk + (size_t)(row - 32) * 512; }
    else               { src = wv + (size_t)(row - 64) * 512; }
    floatx4 v = *(const floatx4*)(src + col);
    union { short s[4]; long long ll; } o;
#pragma unroll
    for (int u = 0; u < 4; u++) o.s[u] = f2bf(v[u] * sc);
    const int didx = (((row >> 6) * 16 + (col >> 5)) * 64 + (row & 63)) * 32 + (col & 31);
    *(long long*)(wb + didx) = o.ll;
}

// ---------------- Projection (R15 version, measured best) ----------------
__global__ __launch_bounds__(256) void proj_kernel(
    const float* __restrict__ x, const short* __restrict__ wb,
    const float* __restrict__ bq, const float* __restrict__ bk,
    const float* __restrict__ bv,
    short* __restrict__ qT, short* __restrict__ kT, short* __restrict__ vm)
{
    __shared__ short xT[32 * 520];   // [n][c] bf16, pitch 520
    const int tid = threadIdx.x;
    const int w = tid >> 6;
    const int lane = tid & 63;
    const int l15 = lane & 15, l4 = lane >> 4;
    const int n0 = blockIdx.x * 32;
    const int og = blockIdx.y;       // 0: ot 0..4, 1: ot 5..8
    const int b  = blockIdx.z;

    const float* xb = x + (size_t)b * 512 * 4096;

    const int cp = tid >> 3;          // 0..31
    const int nq = (tid & 7) * 4;     // 0,4,..,28
#pragma unroll
    for (int p = 0; p < 8; p++) {
        const int c = (p * 32 + cp) * 2;
        const float* r0 = xb + (size_t)c * 4096 + n0 + nq;
        const float* r1 = r0 + 4096;
        floatx4 xa = *(const floatx4*)r0;
        floatx4 xc = *(const floatx4*)r1;
#pragma unroll
        for (int u = 0; u < 4; u++)
            *(unsigned*)&xT[(nq + u) * 520 + c] = cvt_pk_bf16(xa[u], xc[u]);
    }
    __syncthreads();

    const int ot_start = og * 5;          // 0 or 5
    const int ot_count = 5 - og;          // 5 or 4
#pragma unroll 1
    for (int oi = 0; oi < ot_count; oi++) {
        const int ot = ot_start + oi;
        floatx4 acc[2];
#pragma unroll
        for (int i = 0; i < 2; i++) acc[i] = (floatx4)(0.0f);

#pragma unroll 4
        for (int c0 = 0; c0 < 512; c0 += 32) {
            short8 wf = *(const short8*)(wb + ((size_t)(ot * 16 + (c0 >> 5)) * 64
                                               + w * 16 + l15) * 32 + 8 * l4);
#pragma unroll
            for (int nt = 0; nt < 2; nt++) {
                short8 xf = *(const short8*)&xT[(nt * 16 + l15) * 520 + c0 + 8 * l4];
                acc[nt] = mfma16(xf, wf, acc[nt]);   // swapped: D[l15->o][4l4+r->n]
            }
        }

        const int o_d = ot * 64 + w * 16 + l15;
        if (o_d < 32) {
            const float bqe = bq[o_d] * LOG2E;
#pragma unroll
            for (int nt = 0; nt < 2; nt++)
#pragma unroll
                for (int r = 0; r < 4; r++) {
                    const int n = n0 + nt * 16 + 4 * l4 + r;
                    qT[((size_t)(b * 4096 + n)) * 32 + o_d] = f2bf(acc[nt][r] + bqe);
                }
        } else if (o_d < 64) {
            const float bke = bk[o_d - 32];
#pragma unroll
            for (int nt = 0; nt < 2; nt++)
#pragma unroll
                for (int r = 0; r < 4; r++) {
                    const int n = n0 + nt * 16 + 4 * l4 + r;
                    const int s = n & 31;
                    const int p2 = 16 * ((s >> 2) & 1) + 4 * (s >> 3) + (s & 3);
                    const int nst = (n & ~31) | p2;
                    kT[((size_t)(b * 4096 + nst)) * 32 + (o_d - 32)] = f2bf(acc[nt][r] + bke);
                }
        } else {
            const int c = o_d - 64;
            const float bvc = bv[c];
            short* dst = vm + ((size_t)((b * 128 + blockIdx.x) * 512 + c)) * 32;
#pragma unroll
            for (int nt = 0; nt < 2; nt++) {
                union { long long ll; unsigned u2[2]; } pk;
                pk.u2[0] = cvt_pk_bf16(acc[nt][0] + bvc, acc[nt][1] + bvc);
                pk.u2[1] = cvt_pk_bf16(acc[nt][2] + bvc, acc[nt][3] + bvc);
                *(long long*)(dst + nt * 16 + 4 * l4) = pk.ll;
            }
        }
    }
}

// ---------------- Flash attention + residual ----------------
// R17 structure (staggered wave phases + x-prefetch) with LDS-ONLY in-loop
// barriers: s_waitcnt lgkmcnt(0) + raw s_barrier instead of __syncthreads().
// __syncthreads' vmcnt(0) drain was killing every V/K prefetch at each tile
// boundary (the m97-style barrier-drain stall); LDS-only wait keeps global
// loads in flight across tiles. Cross-wave data in the loop is LDS-only.
__global__ __launch_bounds__(512, 1) void attn_kernel(
    const short* __restrict__ qT, const short* __restrict__ kT,
    const short* __restrict__ vm, const float* __restrict__ x,
    const float* __restrict__ gamma, float* __restrict__ out)
{
    __shared__ short P_lds[2][32 * 512];   // [buf][frag = w*4+it][lane*8]  64 KB
    __shared__ float red_lds[8][64];       // 2 KB
    __shared__ short x_lds[512 * 68];      // [c][i_local], pitch 68 -> 69.6 KB
    const int tid = threadIdx.x;
    const int lane = tid & 63;
    const int w = tid >> 6;
    const int l15 = lane & 15, l4 = lane >> 4;

    const int bid = blockIdx.x;
    const int xcd = bid & 7;
    const int idx = bid >> 3;            // 0..31
    const int b   = xcd >> 1;
    const int qt  = (xcd & 1) * 32 + idx;
    const int i0  = qt * 64;
    const int cb  = w * 64;

    short8 qf[4];
#pragma unroll
    for (int it = 0; it < 4; it++)
        qf[it] = *(const short8*)(qT + ((size_t)(b * 4096 + i0 + it * 16 + l15)) * 32 + 8 * l4);

    floatx4 acc[4][4];   // [ct][it]
#pragma unroll
    for (int ct = 0; ct < 4; ct++)
#pragma unroll
        for (int it = 0; it < 4; it++) acc[ct][it] = (floatx4)(0.0f);

    float l_[4] = {0.0f, 0.0f, 0.0f, 0.0f};

    const short* kb = kT + (size_t)b * 4096 * 32;
    const short* vb = vm + (size_t)b * 512 * 4096;   // tiled [jt][512][32]
    const float* xb = x + (size_t)b * 512 * 4096;

#define PROD(T, KF0, KF1)                                                            \
    {                                                                                \
        const int buf = (T) & 1;                                                     \
        _Pragma("unroll")                                                            \
        for (int it = 0; it < 4; it++) {                                             \
            floatx4 s0 = mfma16((KF0), qf[it], (floatx4)(0.0f));                     \
            floatx4 s1 = mfma16((KF1), qf[it], (floatx4)(0.0f));                     \
            float p[8];                                                              \
            _Pragma("unroll")                                                        \
            for (int r = 0; r < 4; r++) {                                            \
                p[r]     = __builtin_amdgcn_exp2f(s0[r]);                            \
                p[4 + r] = __builtin_amdgcn_exp2f(s1[r]);                            \
            }                                                                        \
            union { short8 s; unsigned u[4]; } pk;                                   \
            _Pragma("unroll")                                                        \
            for (int j2 = 0; j2 < 4; j2++) pk.u[j2] = cvt_pk_bf16(p[2*j2], p[2*j2+1]); \
            *(short8*)&P_lds[buf][(w * 4 + it) * 512 + lane * 8] = pk.s;             \
            l_[it] += ((p[0] + p[1]) + (p[2] + p[3])) + ((p[4] + p[5]) + (p[6] + p[7])); \
        }                                                                            \
    }

#define VLOAD(T, JG, CT)                                                             \
    (*(const short8*)(vb + ((size_t)(((T) * 8 + (JG)) * 512 + cb + (CT) * 16 + l15)) * 32 + 8 * l4))
#define PREAD(BUF, JG, IT)                                                           \
    (*(const short8*)&P_lds[BUF][((JG) * 4 + (IT)) * 512 + lane * 8])

#define CONSUME(T)                                                                   \
    {                                                                                \
        const int buf = (T) & 1;                                                     \
        short8 vfp[3][4];                                                            \
        short8 pcp[2][4];                                                            \
        _Pragma("unroll")                                                            \
        for (int ct = 0; ct < 4; ct++) vfp[0][ct] = VLOAD(T, 0, ct);                 \
        _Pragma("unroll")                                                            \
        for (int ct = 0; ct < 4; ct++) vfp[1][ct] = VLOAD(T, 1, ct);                 \
        _Pragma("unroll")                                                            \
        for (int it = 0; it < 4; it++) pcp[0][it] = PREAD(buf, 0, it);               \
        _Pragma("unroll")                                                            \
        for (int jg = 0; jg < 8; jg++) {                                             \
            if (jg < 6) {                                                            \
                _Pragma("unroll")                                                    \
                for (int ct = 0; ct < 4; ct++)                                       \
                    vfp[(jg + 2) % 3][ct] = VLOAD(T, jg + 2, ct);                    \
            }                                                                        \
            if (jg < 7) {                                                            \
                _Pragma("unroll")                                                    \
                for (int it = 0; it < 4; it++)                                       \
                    pcp[(jg + 1) & 1][it] = PREAD(buf, jg + 1, it);                  \
            }                                                                        \
            __builtin_amdgcn_s_setprio(1);                                           \
            _Pragma("unroll")                                                        \
            for (int ct = 0; ct < 4; ct++)                                           \
                _Pragma("unroll")                                                    \
                for (int it = 0; it < 4; it++)                                       \
                    acc[ct][it] = mfma16(vfp[jg % 3][ct], pcp[jg & 1][it], acc[ct][it]); \
            __builtin_amdgcn_s_setprio(0);                                           \
        }                                                                            \
    }

    // prologue: produce macro-tile 0
    {
        short8 kf0 = *(const short8*)(kb + (size_t)(w * 32 + l15) * 32 + 8 * l4);
        short8 kf1 = *(const short8*)(kb + (size_t)(w * 32 + 16 + l15) * 32 + 8 * l4);
        PROD(0, kf0, kf1);
    }

    const bool early = (w < 4);   // wave-uniform phase split

#pragma unroll 1
    for (int t = 0; t < 16; t++) {
        lds_barrier();   // LDS-visibility only; global prefetches stay in flight
        short8 nk0, nk1;
        if (t < 15) {
            const int jj = (t + 1) * 256 + w * 32;
            nk0 = *(const short8*)(kb + (size_t)(jj + l15) * 32 + 8 * l4);
            nk1 = *(const short8*)(kb + (size_t)(jj + 16 + l15) * 32 + 8 * l4);
        }
        if (early) {
            CONSUME(t);
            if (t < 15) PROD(t + 1, nk0, nk1);
        } else {
            if (t < 15) PROD(t + 1, nk0, nk1);
            CONSUME(t);
        }
        if (t == 13) {
            // stage this wave's 64 x-rows into LDS (dwordx4 + cvt_pk + b64)
#pragma unroll
            for (int u = 0; u < 16; u++) {
                const int row = w * 64 + u * 4 + l4;
                floatx4 xv = *(const floatx4*)(xb + (size_t)row * 4096 + i0 + l15 * 4);
                union { long long ll; unsigned u2[2]; } pk;
                pk.u2[0] = cvt_pk_bf16(xv[0], xv[1]);
                pk.u2[1] = cvt_pk_bf16(xv[2], xv[3]);
                *(long long*)&x_lds[row * 68 + l15 * 4] = pk.ll;
            }
        }
    }
#undef PROD
#undef CONSUME
#undef VLOAD
#undef PREAD

    // l: reduce within wave, then across 8 waves via LDS
#pragma unroll
    for (int it = 0; it < 4; it++) {
        l_[it] += __shfl_xor(l_[it], 16, 64);
        l_[it] += __shfl_xor(l_[it], 32, 64);
    }
    if (lane < 16)
#pragma unroll
        for (int it = 0; it < 4; it++) red_lds[w][it * 16 + lane] = l_[it];
    __syncthreads();   // full barrier fine in epilogue (once)

    const float g = gamma[0];
    float inv[4];
#pragma unroll
    for (int it = 0; it < 4; it++) {
        float s = 0.0f;
#pragma unroll
        for (int ww = 0; ww < 8; ww++) s += red_lds[ww][it * 16 + l15];
        inv[it] = g / s;
    }

#pragma unroll
    for (int ct = 0; ct < 4; ct++)
#pragma unroll
        for (int it = 0; it < 4; it++)
#pragma unroll
            for (int r = 0; r < 4; r++) {
                const int c = cb + ct * 16 + 4 * l4 + r;
                const int i = i0 + it * 16 + l15;
                const size_t o = ((size_t)(b * 512 + c)) * 4096 + i;
                out[o] = acc[ct][it][r] * inv[it] + bf2f(x_lds[c * 68 + it * 16 + l15]);
            }
}

extern "C" void kernel_launch(void* const* d_in, const int* in_sizes, int n_in,
                              void* d_out, int out_size, void* d_ws, size_t ws_size,
                              hipStream_t stream) {
    const float* x     = (const float*)d_in[0];
    const float* wq    = (const float*)d_in[1];
    const float* bq    = (const float*)d_in[2];
    const float* wk    = (const float*)d_in[3];
    const float* bk    = (const float*)d_in[4];
    const float* wv    = (const float*)d_in[5];
    const float* bv    = (const float*)d_in[6];
    const float* gamma = (const float*)d_in[7];
    float* out = (float*)d_out;

    short* qT = (short*)d_ws;                  // 1 MB
    short* kT = qT + (size_t)4 * 4096 * 32;    // 1 MB
    short* vm = kT + (size_t)4 * 4096 * 32;    // 16 MB (tiled [b][jt][512][32])
    short* wb = vm + (size_t)4 * 512 * 4096;   // 0.56 MB (tiled)

    wcvt_kernel<<<288, 256, 0, stream>>>(wq, wk, wv, wb);
    proj_kernel<<<dim3(128, 2, 4), 256, 0, stream>>>(x, wb, bq, bk, bv, qT, kT, vm);
    attn_kernel<<<256, 512, 0, stream>>>(qT, kT, vm, x, gamma, out);
}